// Round 2
// baseline (1809.664 us; speedup 1.0000x reference)
//
#include <hip/hip_runtime.h>
#include <math.h>

#define DMODEL 512
#define NSEQ 2048
#define NHEAD 8
#define DK 64
#define DV 64
#define MFEAT 266
#define MP 272          // padded feature dim (zero tail)
#define NT 32           // number of chunks (chunk = 64)
#define LN_EPS 1e-6f
#define KERNEL_EPS 1e-4f
#define NORM_STAB 1e-6f

typedef __attribute__((ext_vector_type(8))) short short8;
typedef __attribute__((ext_vector_type(4))) float f32x4;

__device__ inline short f2bf(float f) {
    unsigned u = __builtin_bit_cast(unsigned, f);
    unsigned r = (u + 0x7fff + ((u >> 16) & 1)) >> 16;
    return (short)r;
}

// ---------------- LayerNorm on q (fp32 out) ----------------
__global__ __launch_bounds__(256) void ln_kernel(const float* __restrict__ q,
                                                 const float* __restrict__ gamma,
                                                 const float* __restrict__ beta,
                                                 float* __restrict__ qn) {
    int row = blockIdx.x;
    int tid = threadIdx.x;
    const float* x = q + (size_t)row * DMODEL;
    float x0 = x[tid], x1 = x[tid + 256];
    float s = x0 + x1, ss = x0 * x0 + x1 * x1;
    for (int o = 32; o > 0; o >>= 1) {
        s += __shfl_down(s, o);
        ss += __shfl_down(ss, o);
    }
    __shared__ float sbuf[4], ssbuf[4];
    __shared__ float mu_s, rstd_s;
    int wid = tid >> 6, lane = tid & 63;
    if (lane == 0) { sbuf[wid] = s; ssbuf[wid] = ss; }
    __syncthreads();
    if (tid == 0) {
        float st = sbuf[0] + sbuf[1] + sbuf[2] + sbuf[3];
        float sst = ssbuf[0] + ssbuf[1] + ssbuf[2] + ssbuf[3];
        float mu = st / (float)DMODEL;
        float var = sst / (float)DMODEL - mu * mu;
        mu_s = mu;
        rstd_s = rsqrtf(var + LN_EPS);
    }
    __syncthreads();
    float mu = mu_s, rstd = rstd_s;
    qn[(size_t)row * DMODEL + tid] = (x0 - mu) * rstd * gamma[tid] + beta[tid];
    qn[(size_t)row * DMODEL + tid + 256] = (x1 - mu) * rstd * gamma[tid + 256] + beta[tid + 256];
}

// ---------------- bf16 MFMA GEMM: C = (A @ (scale*B)) [+bias][+residual] ----------------
// A fp32 [Mr][Kr] row-major (cast to bf16 in staging), B fp32 [Kr][Nr] row-major
// (transposed+cast+scaled in staging), C fp32 [Mr][Nr]. Mr%64==0, Nr%64==0, Kr%32==0.
__global__ __launch_bounds__(256) void mgemm_kernel(const float* __restrict__ A,
                                                    const float* __restrict__ B,
                                                    float* __restrict__ C,
                                                    int Mr, int Nr, int Kr, float scale,
                                                    const float* __restrict__ bias,
                                                    const float* __restrict__ residual) {
    __shared__ short As[64][40];  // [row][k] bf16, padded stride 40 (80B)
    __shared__ short Bs[64][40];  // [col][k] bf16
    int bm = blockIdx.y * 64, bn = blockIdx.x * 64;
    int tid = threadIdx.x;
    int wid = tid >> 6, lane = tid & 63;
    f32x4 acc[4] = {f32x4{0,0,0,0}, f32x4{0,0,0,0}, f32x4{0,0,0,0}, f32x4{0,0,0,0}};
    int ar = tid >> 2, akq = tid & 3;        // A staging: row 0..63, k-quad 0..3 (8 k each)
    int bkk = tid >> 3, bng = tid & 7;       // B staging: k 0..31, n-group 0..7 (8 n each)
    for (int k0 = 0; k0 < Kr; k0 += 32) {
        // stage A: 64 rows x 32 k
        {
            const float* src = A + (size_t)(bm + ar) * Kr + k0 + akq * 8;
            f32x4 v0 = *(const f32x4*)src;
            f32x4 v1 = *(const f32x4*)(src + 4);
            short8 sv;
            for (int j = 0; j < 4; ++j) { sv[j] = f2bf(v0[j]); sv[4 + j] = f2bf(v1[j]); }
            *(short8*)&As[ar][akq * 8] = sv;
        }
        // stage B transposed: Bs[n][k] from B[k][n], with scale
        {
            const float* src = B + (size_t)(k0 + bkk) * Nr + bn + bng * 8;
            f32x4 v0 = *(const f32x4*)src;
            f32x4 v1 = *(const f32x4*)(src + 4);
            for (int j = 0; j < 4; ++j) {
                Bs[bng * 8 + j][bkk] = f2bf(v0[j] * scale);
                Bs[bng * 8 + 4 + j][bkk] = f2bf(v1[j] * scale);
            }
        }
        __syncthreads();
        int row = wid * 16 + (lane & 15);
        int koff = (lane >> 4) * 8;
        short8 a = *(const short8*)&As[row][koff];
        for (int nf = 0; nf < 4; ++nf) {
            int col = nf * 16 + (lane & 15);
            short8 b = *(const short8*)&Bs[col][koff];
            acc[nf] = __builtin_amdgcn_mfma_f32_16x16x32_bf16(a, b, acc[nf], 0, 0, 0);
        }
        __syncthreads();
    }
    for (int nf = 0; nf < 4; ++nf) {
        int col = bn + nf * 16 + (lane & 15);
        for (int j = 0; j < 4; ++j) {
            int row = bm + wid * 16 + (lane >> 4) * 4 + j;
            float v = acc[nf][j];
            if (bias) v += bias[col];
            if (residual) v += residual[(size_t)row * Nr + col];
            C[(size_t)row * Nr + col] = v;
        }
    }
}

// ---------------- h_k + global max partials ----------------
__global__ __launch_bounds__(256) void hk_kernel(const float* __restrict__ kh,
                                                 float* __restrict__ hk,
                                                 float* __restrict__ partial) {
    int idx = blockIdx.x * 256 + threadIdx.x;  // 0..16383
    int n = idx >> 3, h = idx & 7;
    const float* row = kh + (size_t)n * DMODEL + h * DK;
    float s = 0.f;
    for (int d = 0; d < DK; d += 4) {
        f32x4 v = *(const f32x4*)(row + d);
        s += v[0] * v[0] + v[1] * v[1] + v[2] * v[2] + v[3] * v[3];
    }
    float hv = -0.5f * s;
    hk[(size_t)h * NSEQ + n] = hv;
    float m = hv;
    for (int o = 32; o > 0; o >>= 1) m = fmaxf(m, __shfl_down(m, o));
    __shared__ float wmax[4];
    if ((threadIdx.x & 63) == 0) wmax[threadIdx.x >> 6] = m;
    __syncthreads();
    if (threadIdx.x == 0)
        partial[blockIdx.x] = fmaxf(fmaxf(wmax[0], wmax[1]), fmaxf(wmax[2], wmax[3]));
}

__global__ void maxreduce_kernel(const float* __restrict__ partial, float* __restrict__ kstab) {
    float m = partial[threadIdx.x];  // 64 threads
    for (int o = 32; o > 0; o >>= 1) m = fmaxf(m, __shfl_down(m, o));
    if (threadIdx.x == 0) kstab[0] = m;
}

// ---------------- random feature maps (vectorized GEMM-style) ----------------
// grid (mt=5, nt=32, h=8). Output [h][n][m] padded to MP with zeros.
__global__ __launch_bounds__(256) void feat_kernel(const float* __restrict__ xh,
                                                   const float* __restrict__ rf,
                                                   const float* __restrict__ hkv,
                                                   const float* __restrict__ kstab,
                                                   float* __restrict__ outp, int isQ) {
    int mt = blockIdx.x, nt = blockIdx.y, h = blockIdx.z;
    int n0 = nt * 64, m0 = mt * 64;
    int tid = threadIdx.x;
    int tx = tid & 15, ty = tid >> 4;
    __shared__ float Xs[64][68];  // [d][n]
    __shared__ float Rs[64][68];  // [d][m]
    for (int l = 0; l < 4; ++l) {
        int idx = tid + l * 256;
        int nloc = idx >> 4, dq = idx & 15;
        f32x4 v = *(const f32x4*)&xh[(size_t)(n0 + nloc) * DMODEL + h * DK + dq * 4];
        for (int j = 0; j < 4; ++j) Xs[dq * 4 + j][nloc] = v[j];
        int mloc = nloc;
        int m = m0 + mloc;
        f32x4 rv = {0.f, 0.f, 0.f, 0.f};
        if (m < MFEAT) rv = *(const f32x4*)&rf[(size_t)m * DK + dq * 4];
        for (int j = 0; j < 4; ++j) Rs[dq * 4 + j][mloc] = rv[j];
    }
    __syncthreads();
    float acc[4][4] = {};
    for (int d = 0; d < 64; ++d) {
        f32x4 a = *(const f32x4*)&Xs[d][ty * 4];
        f32x4 b = *(const f32x4*)&Rs[d][tx * 4];
        for (int r = 0; r < 4; ++r)
            for (int c = 0; c < 4; ++c) acc[r][c] += a[r] * b[c];
    }
    const float cnorm = 0.06131393394849658f;  // 266^-0.5
    float ks = kstab[0];
    if (m0 + tx * 4 + 3 < MP) {
        for (int r = 0; r < 4; ++r) {
            int n = n0 + ty * 4 + r;
            float hval = isQ ? 0.f : hkv[(size_t)h * NSEQ + n] - ks;
            f32x4 o;
            for (int c = 0; c < 4; ++c) {
                int mg = m0 + tx * 4 + c;
                o[c] = (mg < MFEAT) ? cnorm * (expf(acc[r][c] + hval) + KERNEL_EPS) : 0.f;
            }
            *(f32x4*)&outp[((size_t)h * NSEQ + n) * MP + m0 + tx * 4] = o;
        }
    }
}

// ---------------- phase A: per-chunk sums KV[m][dv], Ks[m] ----------------
__global__ __launch_bounds__(256) void chunksum_kernel(const float* __restrict__ kp,
                                                       const float* __restrict__ vh,
                                                       float* __restrict__ KV,
                                                       float* __restrict__ Ks) {
    int mt = blockIdx.x, t = blockIdx.y, h = blockIdx.z;
    int m0 = mt * 64;
    int tid = threadIdx.x;
    int tx = tid & 15, ty = tid >> 4;
    __shared__ float Kl[64][68];  // [i][mloc]
    __shared__ float Vl[64][68];  // [i][dv]
    for (int l = 0; l < 4; ++l) {
        int idx = tid + l * 256;
        int i = idx >> 4, q4 = idx & 15;
        int m = m0 + q4 * 4;
        f32x4 kv = {0.f, 0.f, 0.f, 0.f};
        if (m + 3 < MP) kv = *(const f32x4*)&kp[((size_t)h * NSEQ + t * 64 + i) * MP + m];
        *(f32x4*)&Kl[i][q4 * 4] = kv;
        f32x4 vv = *(const f32x4*)&vh[(size_t)(t * 64 + i) * DMODEL + h * DV + q4 * 4];
        *(f32x4*)&Vl[i][q4 * 4] = vv;
    }
    __syncthreads();
    float acc[4][4] = {};
    for (int i = 0; i < 64; ++i) {
        f32x4 a = *(const f32x4*)&Kl[i][ty * 4];
        f32x4 b = *(const f32x4*)&Vl[i][tx * 4];
        for (int r = 0; r < 4; ++r)
            for (int c = 0; c < 4; ++c) acc[r][c] += a[r] * b[c];
    }
    for (int r = 0; r < 4; ++r) {
        int m = m0 + ty * 4 + r;
        if (m < MP) {
            f32x4 o;
            for (int c = 0; c < 4; ++c) o[c] = acc[r][c];
            *(f32x4*)&KV[(((size_t)h * NT + t) * MP + m) * DV + tx * 4] = o;
        }
    }
    if (tid < 64) {
        int m = m0 + tid;
        if (m < MP) {
            float s = 0.f;
            for (int i = 0; i < 64; ++i) s += Kl[i][tid];
            Ks[((size_t)h * NT + t) * MP + m] = s;
        }
    }
}

// ---------------- exclusive prefix over chunks (in place) ----------------
__global__ void scankv_kernel(float* __restrict__ KV) {
    int idx = blockIdx.x * 256 + threadIdx.x;
    if (idx >= NHEAD * MP * DV) return;
    int h = idx / (MP * DV);
    int rem = idx % (MP * DV);
    size_t base = (size_t)h * NT * MP * DV + rem;
    float run = 0.f;
    for (int t = 0; t < NT; ++t) {
        size_t o = base + (size_t)t * MP * DV;
        float v = KV[o];
        KV[o] = run;
        run += v;
    }
}

__global__ void scanks_kernel(float* __restrict__ Ks, float* __restrict__ Ktot) {
    int idx = blockIdx.x * 256 + threadIdx.x;
    if (idx >= NHEAD * MP) return;
    int h = idx / MP, m = idx % MP;
    size_t base = (size_t)h * NT * MP + m;
    float run = 0.f;
    for (int t = 0; t < NT; ++t) {
        size_t o = base + (size_t)t * MP;
        float v = Ks[o];
        Ks[o] = run;
        run += v;
    }
    Ktot[(size_t)h * MP + m] = run;
}

// ---------------- phase C: intra-chunk causal + inter-chunk state + denominators ----------------
__global__ __launch_bounds__(256) void phasec_kernel(const float* __restrict__ qp,
                                                     const float* __restrict__ kp,
                                                     const float* __restrict__ vh,
                                                     const float* __restrict__ KV,
                                                     const float* __restrict__ Ks,
                                                     const float* __restrict__ Ktot,
                                                     float* __restrict__ attn) {
    int t = blockIdx.x, h = blockIdx.y;
    int tid = threadIdx.x;
    int tx = tid & 15, ty = tid >> 4;
    __shared__ float Qs[16][68];   // [k][row]
    __shared__ float Kh[16][68];   // [k][col]
    __shared__ float Ss[16][68];   // [k][dv]
    __shared__ float Amat[64][68];
    __shared__ float Vl[64][68];
    __shared__ float rowsum_s[64], fscale_s[64];
    const float* qpb = qp + ((size_t)h * NSEQ + t * 64) * MP;
    const float* kpb = kp + ((size_t)h * NSEQ + t * 64) * MP;
    const float* Sp = KV + ((size_t)h * NT + t) * MP * DV;

    float accA[4][4] = {};
    float accO[4][4] = {};
    int r4 = tid >> 2, kq = tid & 3;
    int skk = tid >> 4, sdq = tid & 15;
    for (int s = 0; s < 17; ++s) {
        int m0 = s * 16;
        __syncthreads();
        f32x4 qv = *(const f32x4*)&qpb[(size_t)r4 * MP + m0 + kq * 4];
        f32x4 kv = *(const f32x4*)&kpb[(size_t)r4 * MP + m0 + kq * 4];
        for (int j = 0; j < 4; ++j) {
            Qs[kq * 4 + j][r4] = qv[j];
            Kh[kq * 4 + j][r4] = kv[j];
        }
        f32x4 sv = *(const f32x4*)&Sp[(size_t)(m0 + skk) * DV + sdq * 4];
        *(f32x4*)&Ss[skk][sdq * 4] = sv;
        __syncthreads();
        for (int kk = 0; kk < 16; ++kk) {
            f32x4 a = *(const f32x4*)&Qs[kk][ty * 4];
            f32x4 bk = *(const f32x4*)&Kh[kk][tx * 4];
            f32x4 bs = *(const f32x4*)&Ss[kk][tx * 4];
            for (int r = 0; r < 4; ++r)
                for (int c = 0; c < 4; ++c) {
                    accA[r][c] += a[r] * bk[c];
                    accO[r][c] += a[r] * bs[c];
                }
        }
    }
    __syncthreads();
    for (int r = 0; r < 4; ++r)
        for (int c = 0; c < 4; ++c) Amat[ty * 4 + r][tx * 4 + c] = accA[r][c];
    // stage sprev(272) + ktot(272) into scratch (overlays Qs+Kh region via Qs base)
    float* scratch = &Qs[0][0];  // 16*68 = 1088 floats available
    for (int l = 0; l < 3; ++l) {
        int idx = tid + l * 256;
        if (idx < 272) scratch[idx] = Ks[((size_t)h * NT + t) * MP + idx];
        else if (idx < 544) scratch[idx] = Ktot[(size_t)h * MP + (idx - 272)];
    }
    __syncthreads();
    if (tid < 64) {
        float s = 0.f;
        for (int j = 0; j <= tid; ++j) s += Amat[tid][j];
        rowsum_s[tid] = s;
    }
    // denominators: i = tid>>2 row, p = tid&3 partial over m-range [p*68, p*68+68)
    int di = tid >> 2, dp = tid & 3;
    float dcp = 0.f, df = 0.f;
    for (int sb = 0; sb < 17; ++sb) {
        int m = dp * 68 + sb * 4;
        f32x4 qv = *(const f32x4*)&qpb[(size_t)di * MP + m];
        f32x4 a = *(const f32x4*)&scratch[m];
        f32x4 b = *(const f32x4*)&scratch[272 + m];
        for (int j = 0; j < 4; ++j) { dcp += qv[j] * a[j]; df += qv[j] * b[j]; }
    }
    dcp += __shfl_xor(dcp, 1); dcp += __shfl_xor(dcp, 2);
    df += __shfl_xor(df, 1); df += __shfl_xor(df, 2);
    __syncthreads();
    if (dp == 0) {
        float dc = rowsum_s[di] + dcp;
        float dst = df;
        if (fabsf(dst) <= NORM_STAB) dst += 2.f * NORM_STAB;
        fscale_s[di] = (1.f / dc) / dst;
    }
    for (int l = 0; l < 4; ++l) {
        int idx = tid + l * 256;
        int i = idx >> 4, dq = idx & 15;
        f32x4 vv = *(const f32x4*)&vh[(size_t)(t * 64 + i) * DMODEL + h * DV + dq * 4];
        *(f32x4*)&Vl[i][dq * 4] = vv;
    }
    __syncthreads();
    // intra: (A masked) @ V
    for (int j = 0; j < 64; ++j) {
        f32x4 b = *(const f32x4*)&Vl[j][tx * 4];
        for (int r = 0; r < 4; ++r) {
            int i = ty * 4 + r;
            if (j <= i) {
                float a = Amat[i][j];
                for (int c = 0; c < 4; ++c) accO[r][c] += a * b[c];
            }
        }
    }
    for (int r = 0; r < 4; ++r) {
        int i = ty * 4 + r;
        float fs = fscale_s[i];
        int n = t * 64 + i;
        f32x4 o;
        for (int c = 0; c < 4; ++c) o[c] = accO[r][c] * fs;
        *(f32x4*)&attn[(size_t)n * DMODEL + h * DV + tx * 4] = o;
    }
}

extern "C" void kernel_launch(void* const* d_in, const int* in_sizes, int n_in,
                              void* d_out, int out_size, void* d_ws, size_t ws_size,
                              hipStream_t stream) {
    const float* q = (const float*)d_in[0];
    const float* k = (const float*)d_in[1];
    const float* v = (const float*)d_in[2];
    const float* Wq = (const float*)d_in[3];
    const float* Wk = (const float*)d_in[4];
    const float* Wv = (const float*)d_in[5];
    const float* Wfc = (const float*)d_in[6];
    const float* bfc = (const float*)d_in[7];
    const float* gamma = (const float*)d_in[8];
    const float* beta = (const float*)d_in[9];
    const float* rf = (const float*)d_in[10];
    float* out = (float*)d_out;

    float* ws = (float*)d_ws;
    float* qn = ws;                                      // 2048*512 (reused as attn out)
    float* qh = qn + (size_t)NSEQ * DMODEL;              // 2048*512
    float* kh = qh + (size_t)NSEQ * DMODEL;              // 2048*512
    float* vhb = kh + (size_t)NSEQ * DMODEL;             // 2048*512
    float* qp = vhb + (size_t)NSEQ * DMODEL;             // 8*2048*272
    float* kp = qp + (size_t)NHEAD * NSEQ * MP;          // 8*2048*272
    float* KV = kp + (size_t)NHEAD * NSEQ * MP;          // 8*32*272*64
    float* Ks = KV + (size_t)NHEAD * NT * MP * DV;       // 8*32*272
    float* Ktot = Ks + (size_t)NHEAD * NT * MP;          // 8*272
    float* hk = Ktot + (size_t)NHEAD * MP;               // 8*2048
    float* partial = hk + (size_t)NHEAD * NSEQ;          // 64
    float* kstab = partial + 64;                         // 4

    const float scale = 0.21022410381342863f;  // 512^-0.25

    ln_kernel<<<NSEQ, 256, 0, stream>>>(q, gamma, beta, qn);
    dim3 g(DMODEL / 64, NSEQ / 64);
    mgemm_kernel<<<g, 256, 0, stream>>>(qn, Wq, qh, NSEQ, DMODEL, DMODEL, scale, nullptr, nullptr);
    mgemm_kernel<<<g, 256, 0, stream>>>(k, Wk, kh, NSEQ, DMODEL, DMODEL, scale, nullptr, nullptr);
    mgemm_kernel<<<g, 256, 0, stream>>>(v, Wv, vhb, NSEQ, DMODEL, DMODEL, 1.f, nullptr, nullptr);
    hk_kernel<<<64, 256, 0, stream>>>(kh, hk, partial);
    maxreduce_kernel<<<1, 64, 0, stream>>>(partial, kstab);
    dim3 gf(5, NSEQ / 64, NHEAD);
    feat_kernel<<<gf, 256, 0, stream>>>(qh, rf, hk, kstab, qp, 1);
    feat_kernel<<<gf, 256, 0, stream>>>(kh, rf, hk, kstab, kp, 0);
    dim3 ga(5, NT, NHEAD);
    chunksum_kernel<<<ga, 256, 0, stream>>>(kp, vhb, KV, Ks);
    scankv_kernel<<<(NHEAD * MP * DV + 255) / 256, 256, 0, stream>>>(KV);
    scanks_kernel<<<(NHEAD * MP + 255) / 256, 256, 0, stream>>>(Ks, Ktot);
    dim3 gc(NT, NHEAD);
    phasec_kernel<<<gc, 256, 0, stream>>>(qp, kp, vhb, KV, Ks, Ktot, qn);
    mgemm_kernel<<<g, 256, 0, stream>>>(qn, Wfc, out, NSEQ, DMODEL, DMODEL, 1.f, bfc, q);
}

// Round 4
// 211.169 us; speedup vs baseline: 8.5698x; 8.5698x over previous
//
#include <hip/hip_runtime.h>
#include <math.h>

#define DMODEL 512
#define NSEQ 2048
#define NHEAD 8
#define DK 64
#define DV 64
#define MFEAT 266
#define MP 272          // padded feature dim (zero tail)
#define NT 32           // number of chunks (chunk = 64)
#define LN_EPS 1e-6f
#define KERNEL_EPS 1e-4f
#define NORM_STAB 1e-6f

typedef __attribute__((ext_vector_type(8))) short short8;
typedef __attribute__((ext_vector_type(4))) float f32x4;

__device__ inline short f2bf(float f) {
    unsigned u = __builtin_bit_cast(unsigned, f);
    unsigned r = (u + 0x7fff + ((u >> 16) & 1)) >> 16;
    return (short)r;
}

// ---------------- LayerNorm on q (fp32 out) ----------------
__global__ __launch_bounds__(256) void ln_kernel(const float* __restrict__ q,
                                                 const float* __restrict__ gamma,
                                                 const float* __restrict__ beta,
                                                 float* __restrict__ qn) {
    int row = blockIdx.x;
    int tid = threadIdx.x;
    const float* x = q + (size_t)row * DMODEL;
    float x0 = x[tid], x1 = x[tid + 256];
    float s = x0 + x1, ss = x0 * x0 + x1 * x1;
    for (int o = 32; o > 0; o >>= 1) {
        s += __shfl_down(s, o);
        ss += __shfl_down(ss, o);
    }
    __shared__ float sbuf[4], ssbuf[4];
    __shared__ float mu_s, rstd_s;
    int wid = tid >> 6, lane = tid & 63;
    if (lane == 0) { sbuf[wid] = s; ssbuf[wid] = ss; }
    __syncthreads();
    if (tid == 0) {
        float st = sbuf[0] + sbuf[1] + sbuf[2] + sbuf[3];
        float sst = ssbuf[0] + ssbuf[1] + ssbuf[2] + ssbuf[3];
        float mu = st / (float)DMODEL;
        float var = sst / (float)DMODEL - mu * mu;
        mu_s = mu;
        rstd_s = rsqrtf(var + LN_EPS);
    }
    __syncthreads();
    float mu = mu_s, rstd = rstd_s;
    qn[(size_t)row * DMODEL + tid] = (x0 - mu) * rstd * gamma[tid] + beta[tid];
    qn[(size_t)row * DMODEL + tid + 256] = (x1 - mu) * rstd * gamma[tid + 256] + beta[tid + 256];
}

// ---------------- bf16 MFMA GEMM: C = (A @ (scale*B)) [+bias][+residual] ----------------
__global__ __launch_bounds__(256) void mgemm_kernel(const float* __restrict__ A,
                                                    const float* __restrict__ B,
                                                    float* __restrict__ C,
                                                    int Mr, int Nr, int Kr, float scale,
                                                    const float* __restrict__ bias,
                                                    const float* __restrict__ residual) {
    __shared__ short As[64][40];  // [row][k] bf16, padded stride 40 (80B)
    __shared__ short Bs[64][40];  // [col][k] bf16
    int bm = blockIdx.y * 64, bn = blockIdx.x * 64;
    int tid = threadIdx.x;
    int wid = tid >> 6, lane = tid & 63;
    f32x4 acc[4] = {f32x4{0,0,0,0}, f32x4{0,0,0,0}, f32x4{0,0,0,0}, f32x4{0,0,0,0}};
    int ar = tid >> 2, akq = tid & 3;        // A staging: row 0..63, k-quad 0..3 (8 k each)
    int bkk = tid >> 3, bng = tid & 7;       // B staging: k 0..31, n-group 0..7 (8 n each)
    for (int k0 = 0; k0 < Kr; k0 += 32) {
        {
            const float* src = A + (size_t)(bm + ar) * Kr + k0 + akq * 8;
            f32x4 v0 = *(const f32x4*)src;
            f32x4 v1 = *(const f32x4*)(src + 4);
            short8 sv;
            for (int j = 0; j < 4; ++j) { sv[j] = f2bf(v0[j]); sv[4 + j] = f2bf(v1[j]); }
            *(short8*)&As[ar][akq * 8] = sv;
        }
        {
            const float* src = B + (size_t)(k0 + bkk) * Nr + bn + bng * 8;
            f32x4 v0 = *(const f32x4*)src;
            f32x4 v1 = *(const f32x4*)(src + 4);
            for (int j = 0; j < 4; ++j) {
                Bs[bng * 8 + j][bkk] = f2bf(v0[j] * scale);
                Bs[bng * 8 + 4 + j][bkk] = f2bf(v1[j] * scale);
            }
        }
        __syncthreads();
        int row = wid * 16 + (lane & 15);
        int koff = (lane >> 4) * 8;
        short8 a = *(const short8*)&As[row][koff];
        for (int nf = 0; nf < 4; ++nf) {
            int col = nf * 16 + (lane & 15);
            short8 b = *(const short8*)&Bs[col][koff];
            acc[nf] = __builtin_amdgcn_mfma_f32_16x16x32_bf16(a, b, acc[nf], 0, 0, 0);
        }
        __syncthreads();
    }
    for (int nf = 0; nf < 4; ++nf) {
        int col = bn + nf * 16 + (lane & 15);
        for (int j = 0; j < 4; ++j) {
            int row = bm + wid * 16 + (lane >> 4) * 4 + j;
            float v = acc[nf][j];
            if (bias) v += bias[col];
            if (residual) v += residual[(size_t)row * Nr + col];
            C[(size_t)row * Nr + col] = v;
        }
    }
}

// ---------------- h_k + global max partials ----------------
__global__ __launch_bounds__(256) void hk_kernel(const float* __restrict__ kh,
                                                 float* __restrict__ hk,
                                                 float* __restrict__ partial) {
    int idx = blockIdx.x * 256 + threadIdx.x;  // 0..16383
    int n = idx >> 3, h = idx & 7;
    const float* row = kh + (size_t)n * DMODEL + h * DK;
    float s = 0.f;
    for (int d = 0; d < DK; d += 4) {
        f32x4 v = *(const f32x4*)(row + d);
        s += v[0] * v[0] + v[1] * v[1] + v[2] * v[2] + v[3] * v[3];
    }
    float hv = -0.5f * s;
    hk[(size_t)h * NSEQ + n] = hv;
    float m = hv;
    for (int o = 32; o > 0; o >>= 1) m = fmaxf(m, __shfl_down(m, o));
    __shared__ float wmax[4];
    if ((threadIdx.x & 63) == 0) wmax[threadIdx.x >> 6] = m;
    __syncthreads();
    if (threadIdx.x == 0)
        partial[blockIdx.x] = fmaxf(fmaxf(wmax[0], wmax[1]), fmaxf(wmax[2], wmax[3]));
}

__global__ void maxreduce_kernel(const float* __restrict__ partial, float* __restrict__ kstab) {
    float m = partial[threadIdx.x];  // 64 threads
    for (int o = 32; o > 0; o >>= 1) m = fmaxf(m, __shfl_down(m, o));
    if (threadIdx.x == 0) kstab[0] = m;
}

// ---------------- random feature maps (vectorized GEMM-style, unroll-capped) ----------------
__global__ __launch_bounds__(256) void feat_kernel(const float* __restrict__ xh,
                                                   const float* __restrict__ rf,
                                                   const float* __restrict__ hkv,
                                                   const float* __restrict__ kstab,
                                                   float* __restrict__ outp, int isQ) {
    int mt = blockIdx.x, nt = blockIdx.y, h = blockIdx.z;
    int n0 = nt * 64, m0 = mt * 64;
    int tid = threadIdx.x;
    int tx = tid & 15, ty = tid >> 4;
    __shared__ float Xs[64][68];  // [d][n]
    __shared__ float Rs[64][68];  // [d][m]
    for (int l = 0; l < 4; ++l) {
        int idx = tid + l * 256;
        int nloc = idx >> 4, dq = idx & 15;
        f32x4 v = *(const f32x4*)&xh[(size_t)(n0 + nloc) * DMODEL + h * DK + dq * 4];
        for (int j = 0; j < 4; ++j) Xs[dq * 4 + j][nloc] = v[j];
        int mloc = nloc;
        int m = m0 + mloc;
        f32x4 rv = {0.f, 0.f, 0.f, 0.f};
        if (m < MFEAT) rv = *(const f32x4*)&rf[(size_t)m * DK + dq * 4];
        for (int j = 0; j < 4; ++j) Rs[dq * 4 + j][mloc] = rv[j];
    }
    __syncthreads();
    float acc[4][4] = {};
#pragma unroll 4
    for (int d = 0; d < 64; ++d) {
        f32x4 a = *(const f32x4*)&Xs[d][ty * 4];
        f32x4 b = *(const f32x4*)&Rs[d][tx * 4];
        for (int r = 0; r < 4; ++r)
            for (int c = 0; c < 4; ++c) acc[r][c] += a[r] * b[c];
    }
    const float cnorm = 0.06131393394849658f;  // 266^-0.5
    float ks = kstab[0];
    if (m0 + tx * 4 + 3 < MP) {
        for (int r = 0; r < 4; ++r) {
            int n = n0 + ty * 4 + r;
            float hval = isQ ? 0.f : hkv[(size_t)h * NSEQ + n] - ks;
            f32x4 o;
            for (int c = 0; c < 4; ++c) {
                int mg = m0 + tx * 4 + c;
                o[c] = (mg < MFEAT) ? cnorm * (expf(acc[r][c] + hval) + KERNEL_EPS) : 0.f;
            }
            *(f32x4*)&outp[((size_t)h * NSEQ + n) * MP + m0 + tx * 4] = o;
        }
    }
}

// ---------------- phase A: per-chunk sums KV[m][dv], Ks[m] ----------------
__global__ __launch_bounds__(256) void chunksum_kernel(const float* __restrict__ kp,
                                                       const float* __restrict__ vh,
                                                       float* __restrict__ KV,
                                                       float* __restrict__ Ks) {
    int mt = blockIdx.x, t = blockIdx.y, h = blockIdx.z;
    int m0 = mt * 64;
    int tid = threadIdx.x;
    int tx = tid & 15, ty = tid >> 4;
    __shared__ float Kl[64][68];  // [i][mloc]
    __shared__ float Vl[64][68];  // [i][dv]
    for (int l = 0; l < 4; ++l) {
        int idx = tid + l * 256;
        int i = idx >> 4, q4 = idx & 15;
        int m = m0 + q4 * 4;
        f32x4 kv = {0.f, 0.f, 0.f, 0.f};
        if (m + 3 < MP) kv = *(const f32x4*)&kp[((size_t)h * NSEQ + t * 64 + i) * MP + m];
        *(f32x4*)&Kl[i][q4 * 4] = kv;
        f32x4 vv = *(const f32x4*)&vh[(size_t)(t * 64 + i) * DMODEL + h * DV + q4 * 4];
        *(f32x4*)&Vl[i][q4 * 4] = vv;
    }
    __syncthreads();
    float acc[4][4] = {};
#pragma unroll 4
    for (int i = 0; i < 64; ++i) {
        f32x4 a = *(const f32x4*)&Kl[i][ty * 4];
        f32x4 b = *(const f32x4*)&Vl[i][tx * 4];
        for (int r = 0; r < 4; ++r)
            for (int c = 0; c < 4; ++c) acc[r][c] += a[r] * b[c];
    }
    for (int r = 0; r < 4; ++r) {
        int m = m0 + ty * 4 + r;
        if (m < MP) {
            f32x4 o;
            for (int c = 0; c < 4; ++c) o[c] = acc[r][c];
            *(f32x4*)&KV[(((size_t)h * NT + t) * MP + m) * DV + tx * 4] = o;
        }
    }
    if (tid < 64) {
        int m = m0 + tid;
        if (m < MP) {
            float s = 0.f;
#pragma unroll 8
            for (int i = 0; i < 64; ++i) s += Kl[i][tid];
            Ks[((size_t)h * NT + t) * MP + m] = s;
        }
    }
}

// ---------------- exclusive prefix over chunks (in place) ----------------
__global__ void scankv_kernel(float* __restrict__ KV) {
    int idx = blockIdx.x * 256 + threadIdx.x;
    if (idx >= NHEAD * MP * DV) return;
    int h = idx / (MP * DV);
    int rem = idx % (MP * DV);
    size_t base = (size_t)h * NT * MP * DV + rem;
    float run = 0.f;
    for (int t = 0; t < NT; ++t) {
        size_t o = base + (size_t)t * MP * DV;
        float v = KV[o];
        KV[o] = run;
        run += v;
    }
}

__global__ void scanks_kernel(float* __restrict__ Ks, float* __restrict__ Ktot) {
    int idx = blockIdx.x * 256 + threadIdx.x;
    if (idx >= NHEAD * MP) return;
    int h = idx / MP, m = idx % MP;
    size_t base = (size_t)h * NT * MP + m;
    float run = 0.f;
    for (int t = 0; t < NT; ++t) {
        size_t o = base + (size_t)t * MP;
        float v = Ks[o];
        Ks[o] = run;
        run += v;
    }
    Ktot[(size_t)h * MP + m] = run;
}

// ---------------- phase C: intra-chunk causal + inter-chunk state + denominators ----------------
__global__ __launch_bounds__(256) void phasec_kernel(const float* __restrict__ qp,
                                                     const float* __restrict__ kp,
                                                     const float* __restrict__ vh,
                                                     const float* __restrict__ KV,
                                                     const float* __restrict__ Ks,
                                                     const float* __restrict__ Ktot,
                                                     float* __restrict__ attn) {
    int t = blockIdx.x, h = blockIdx.y;
    int tid = threadIdx.x;
    int tx = tid & 15, ty = tid >> 4;
    __shared__ float Qs[16][68];   // [k][row]
    __shared__ float Kh[16][68];   // [k][col]
    __shared__ float Ss[16][68];   // [k][dv]
    __shared__ float Amat[64][68];
    __shared__ float Vl[64][68];
    __shared__ float rowsum_s[64], fscale_s[64];
    const float* qpb = qp + ((size_t)h * NSEQ + t * 64) * MP;
    const float* kpb = kp + ((size_t)h * NSEQ + t * 64) * MP;
    const float* Sp = KV + ((size_t)h * NT + t) * MP * DV;

    float accA[4][4] = {};
    float accO[4][4] = {};
    int r4 = tid >> 2, kq = tid & 3;
    int skk = tid >> 4, sdq = tid & 15;
#pragma unroll 1
    for (int s = 0; s < 17; ++s) {
        int m0 = s * 16;
        __syncthreads();
        f32x4 qv = *(const f32x4*)&qpb[(size_t)r4 * MP + m0 + kq * 4];
        f32x4 kv = *(const f32x4*)&kpb[(size_t)r4 * MP + m0 + kq * 4];
        for (int j = 0; j < 4; ++j) {
            Qs[kq * 4 + j][r4] = qv[j];
            Kh[kq * 4 + j][r4] = kv[j];
        }
        f32x4 sv = *(const f32x4*)&Sp[(size_t)(m0 + skk) * DV + sdq * 4];
        *(f32x4*)&Ss[skk][sdq * 4] = sv;
        __syncthreads();
#pragma unroll 4
        for (int kk = 0; kk < 16; ++kk) {
            f32x4 a = *(const f32x4*)&Qs[kk][ty * 4];
            f32x4 bk = *(const f32x4*)&Kh[kk][tx * 4];
            f32x4 bs = *(const f32x4*)&Ss[kk][tx * 4];
            for (int r = 0; r < 4; ++r)
                for (int c = 0; c < 4; ++c) {
                    accA[r][c] += a[r] * bk[c];
                    accO[r][c] += a[r] * bs[c];
                }
        }
    }
    __syncthreads();
    for (int r = 0; r < 4; ++r)
        for (int c = 0; c < 4; ++c) Amat[ty * 4 + r][tx * 4 + c] = accA[r][c];
    // stage sprev(272) + ktot(272) into scratch (overlays Qs+Kh region via Qs base)
    float* scratch = &Qs[0][0];  // 16*68 = 1088 floats available
    for (int l = 0; l < 3; ++l) {
        int idx = tid + l * 256;
        if (idx < 272) scratch[idx] = Ks[((size_t)h * NT + t) * MP + idx];
        else if (idx < 544) scratch[idx] = Ktot[(size_t)h * MP + (idx - 272)];
    }
    __syncthreads();
    if (tid < 64) {
        float s = 0.f;
        for (int j = 0; j <= tid; ++j) s += Amat[tid][j];
        rowsum_s[tid] = s;
    }
    // denominators: i = tid>>2 row, p = tid&3 partial over m-range [p*68, p*68+68)
    int di = tid >> 2, dp = tid & 3;
    float dcp = 0.f, df = 0.f;
#pragma unroll 4
    for (int sb = 0; sb < 17; ++sb) {
        int m = dp * 68 + sb * 4;
        f32x4 qv = *(const f32x4*)&qpb[(size_t)di * MP + m];
        f32x4 a = *(const f32x4*)&scratch[m];
        f32x4 b = *(const f32x4*)&scratch[272 + m];
        for (int j = 0; j < 4; ++j) { dcp += qv[j] * a[j]; df += qv[j] * b[j]; }
    }
    dcp += __shfl_xor(dcp, 1); dcp += __shfl_xor(dcp, 2);
    df += __shfl_xor(df, 1); df += __shfl_xor(df, 2);
    __syncthreads();
    if (dp == 0) {
        float dc = rowsum_s[di] + dcp;
        float dst = df;
        if (fabsf(dst) <= NORM_STAB) dst += 2.f * NORM_STAB;
        fscale_s[di] = (1.f / dc) / dst;
    }
    for (int l = 0; l < 4; ++l) {
        int idx = tid + l * 256;
        int i = idx >> 4, dq = idx & 15;
        f32x4 vv = *(const f32x4*)&vh[(size_t)(t * 64 + i) * DMODEL + h * DV + dq * 4];
        *(f32x4*)&Vl[i][dq * 4] = vv;
    }
    __syncthreads();
    // intra: (A masked) @ V
#pragma unroll 4
    for (int j = 0; j < 64; ++j) {
        f32x4 b = *(const f32x4*)&Vl[j][tx * 4];
        for (int r = 0; r < 4; ++r) {
            int i = ty * 4 + r;
            if (j <= i) {
                float a = Amat[i][j];
                for (int c = 0; c < 4; ++c) accO[r][c] += a * b[c];
            }
        }
    }
    for (int r = 0; r < 4; ++r) {
        int i = ty * 4 + r;
        float fs = fscale_s[i];
        int n = t * 64 + i;
        f32x4 o;
        for (int c = 0; c < 4; ++c) o[c] = accO[r][c] * fs;
        *(f32x4*)&attn[(size_t)n * DMODEL + h * DV + tx * 4] = o;
    }
}

extern "C" void kernel_launch(void* const* d_in, const int* in_sizes, int n_in,
                              void* d_out, int out_size, void* d_ws, size_t ws_size,
                              hipStream_t stream) {
    const float* q = (const float*)d_in[0];
    const float* k = (const float*)d_in[1];
    const float* v = (const float*)d_in[2];
    const float* Wq = (const float*)d_in[3];
    const float* Wk = (const float*)d_in[4];
    const float* Wv = (const float*)d_in[5];
    const float* Wfc = (const float*)d_in[6];
    const float* bfc = (const float*)d_in[7];
    const float* gamma = (const float*)d_in[8];
    const float* beta = (const float*)d_in[9];
    const float* rf = (const float*)d_in[10];
    float* out = (float*)d_out;

    float* ws = (float*)d_ws;
    float* qn = ws;                                      // 2048*512 (reused as attn out)
    float* qh = qn + (size_t)NSEQ * DMODEL;              // 2048*512
    float* kh = qh + (size_t)NSEQ * DMODEL;              // 2048*512
    float* vhb = kh + (size_t)NSEQ * DMODEL;             // 2048*512
    float* qp = vhb + (size_t)NSEQ * DMODEL;             // 8*2048*272
    float* kp = qp + (size_t)NHEAD * NSEQ * MP;          // 8*2048*272
    float* KV = kp + (size_t)NHEAD * NSEQ * MP;          // 8*32*272*64
    float* Ks = KV + (size_t)NHEAD * NT * MP * DV;       // 8*32*272
    float* Ktot = Ks + (size_t)NHEAD * NT * MP;          // 8*272
    float* hk = Ktot + (size_t)NHEAD * MP;               // 8*2048
    float* partial = hk + (size_t)NHEAD * NSEQ;          // 64
    float* kstab = partial + 64;                         // 4

    const float scale = 0.21022410381342863f;  // 512^-0.25

    ln_kernel<<<NSEQ, 256, 0, stream>>>(q, gamma, beta, qn);
    dim3 g(DMODEL / 64, NSEQ / 64);
    mgemm_kernel<<<g, 256, 0, stream>>>(qn, Wq, qh, NSEQ, DMODEL, DMODEL, scale, nullptr, nullptr);
    mgemm_kernel<<<g, 256, 0, stream>>>(k, Wk, kh, NSEQ, DMODEL, DMODEL, scale, nullptr, nullptr);
    mgemm_kernel<<<g, 256, 0, stream>>>(v, Wv, vhb, NSEQ, DMODEL, DMODEL, 1.f, nullptr, nullptr);
    hk_kernel<<<64, 256, 0, stream>>>(kh, hk, partial);
    maxreduce_kernel<<<1, 64, 0, stream>>>(partial, kstab);
    dim3 gf(5, NSEQ / 64, NHEAD);
    feat_kernel<<<gf, 256, 0, stream>>>(qh, rf, hk, kstab, qp, 1);
    feat_kernel<<<gf, 256, 0, stream>>>(kh, rf, hk, kstab, kp, 0);
    dim3 ga(5, NT, NHEAD);
    chunksum_kernel<<<ga, 256, 0, stream>>>(kp, vhb, KV, Ks);
    scankv_kernel<<<(NHEAD * MP * DV + 255) / 256, 256, 0, stream>>>(KV);
    scanks_kernel<<<(NHEAD * MP + 255) / 256, 256, 0, stream>>>(Ks, Ktot);
    dim3 gc(NT, NHEAD);
    phasec_kernel<<<gc, 256, 0, stream>>>(qp, kp, vhb, KV, Ks, Ktot, qn);
    mgemm_kernel<<<g, 256, 0, stream>>>(qn, Wfc, out, NSEQ, DMODEL, DMODEL, 1.f, bfc, q);
}

// Round 5
// 177.715 us; speedup vs baseline: 10.1829x; 1.1882x over previous
//
#include <hip/hip_runtime.h>
#include <math.h>

#define DMODEL 512
#define NSEQ 2048
#define NHEAD 8
#define DK 64
#define DV 64
#define MFEAT 266
#define MPAD 288        // padded feature dim for bf16 MFMA (zero tail), mult of 32
#define NT 32           // number of chunks (chunk = 64)
#define LN_EPS 1e-6f
#define KERNEL_EPS 1e-4f
#define NORM_STAB 1e-6f

typedef __attribute__((ext_vector_type(8))) short short8;
typedef __attribute__((ext_vector_type(4))) short sv4;
typedef __attribute__((ext_vector_type(4))) float f32x4;

__device__ inline short f2bf(float f) {
    unsigned u = __builtin_bit_cast(unsigned, f);
    unsigned r = (u + 0x7fff + ((u >> 16) & 1)) >> 16;
    return (short)r;
}
__device__ inline float bf2f(short s) {
    unsigned u = ((unsigned)(unsigned short)s) << 16;
    return __builtin_bit_cast(float, u);
}

// ---------------- LayerNorm on q (fp32 out) ----------------
__global__ __launch_bounds__(256) void ln_kernel(const float* __restrict__ q,
                                                 const float* __restrict__ gamma,
                                                 const float* __restrict__ beta,
                                                 float* __restrict__ qn) {
    int row = blockIdx.x;
    int tid = threadIdx.x;
    const float* x = q + (size_t)row * DMODEL;
    float x0 = x[tid], x1 = x[tid + 256];
    float s = x0 + x1, ss = x0 * x0 + x1 * x1;
    for (int o = 32; o > 0; o >>= 1) {
        s += __shfl_down(s, o);
        ss += __shfl_down(ss, o);
    }
    __shared__ float sbuf[4], ssbuf[4];
    __shared__ float mu_s, rstd_s;
    int wid = tid >> 6, lane = tid & 63;
    if (lane == 0) { sbuf[wid] = s; ssbuf[wid] = ss; }
    __syncthreads();
    if (tid == 0) {
        float st = sbuf[0] + sbuf[1] + sbuf[2] + sbuf[3];
        float sst = ssbuf[0] + ssbuf[1] + ssbuf[2] + ssbuf[3];
        float mu = st / (float)DMODEL;
        float var = sst / (float)DMODEL - mu * mu;
        mu_s = mu;
        rstd_s = rsqrtf(var + LN_EPS);
    }
    __syncthreads();
    float mu = mu_s, rstd = rstd_s;
    qn[(size_t)row * DMODEL + tid] = (x0 - mu) * rstd * gamma[tid] + beta[tid];
    qn[(size_t)row * DMODEL + tid + 256] = (x1 - mu) * rstd * gamma[tid + 256] + beta[tid + 256];
}

// ---------------- bf16 MFMA GEMM: C = (A @ (scale*B)) [+bias][+residual] ----------------
__global__ __launch_bounds__(256) void mgemm_kernel(const float* __restrict__ A,
                                                    const float* __restrict__ B,
                                                    float* __restrict__ C,
                                                    int Mr, int Nr, int Kr, float scale,
                                                    const float* __restrict__ bias,
                                                    const float* __restrict__ residual) {
    __shared__ short As[64][40];  // [row][k] bf16, padded stride 40 (80B)
    __shared__ short Bs[64][40];  // [col][k] bf16
    int bm = blockIdx.y * 64, bn = blockIdx.x * 64;
    int tid = threadIdx.x;
    int wid = tid >> 6, lane = tid & 63;
    f32x4 acc[4] = {f32x4{0,0,0,0}, f32x4{0,0,0,0}, f32x4{0,0,0,0}, f32x4{0,0,0,0}};
    int ar = tid >> 2, akq = tid & 3;
    int bkk = tid >> 3, bng = tid & 7;
    for (int k0 = 0; k0 < Kr; k0 += 32) {
        {
            const float* src = A + (size_t)(bm + ar) * Kr + k0 + akq * 8;
            f32x4 v0 = *(const f32x4*)src;
            f32x4 v1 = *(const f32x4*)(src + 4);
            short8 sv;
            for (int j = 0; j < 4; ++j) { sv[j] = f2bf(v0[j]); sv[4 + j] = f2bf(v1[j]); }
            *(short8*)&As[ar][akq * 8] = sv;
        }
        {
            const float* src = B + (size_t)(k0 + bkk) * Nr + bn + bng * 8;
            f32x4 v0 = *(const f32x4*)src;
            f32x4 v1 = *(const f32x4*)(src + 4);
            for (int j = 0; j < 4; ++j) {
                Bs[bng * 8 + j][bkk] = f2bf(v0[j] * scale);
                Bs[bng * 8 + 4 + j][bkk] = f2bf(v1[j] * scale);
            }
        }
        __syncthreads();
        int row = wid * 16 + (lane & 15);
        int koff = (lane >> 4) * 8;
        short8 a = *(const short8*)&As[row][koff];
        for (int nf = 0; nf < 4; ++nf) {
            int col = nf * 16 + (lane & 15);
            short8 b = *(const short8*)&Bs[col][koff];
            acc[nf] = __builtin_amdgcn_mfma_f32_16x16x32_bf16(a, b, acc[nf], 0, 0, 0);
        }
        __syncthreads();
    }
    for (int nf = 0; nf < 4; ++nf) {
        int col = bn + nf * 16 + (lane & 15);
        for (int j = 0; j < 4; ++j) {
            int row = bm + wid * 16 + (lane >> 4) * 4 + j;
            float v = acc[nf][j];
            if (bias) v += bias[col];
            if (residual) v += residual[(size_t)row * Nr + col];
            C[(size_t)row * Nr + col] = v;
        }
    }
}

// ---------------- h_k + global max partials ----------------
__global__ __launch_bounds__(256) void hk_kernel(const float* __restrict__ kh,
                                                 float* __restrict__ hk,
                                                 float* __restrict__ partial) {
    int idx = blockIdx.x * 256 + threadIdx.x;
    int n = idx >> 3, h = idx & 7;
    const float* row = kh + (size_t)n * DMODEL + h * DK;
    float s = 0.f;
    for (int d = 0; d < DK; d += 4) {
        f32x4 v = *(const f32x4*)(row + d);
        s += v[0] * v[0] + v[1] * v[1] + v[2] * v[2] + v[3] * v[3];
    }
    float hv = -0.5f * s;
    hk[(size_t)h * NSEQ + n] = hv;
    float m = hv;
    for (int o = 32; o > 0; o >>= 1) m = fmaxf(m, __shfl_down(m, o));
    __shared__ float wmax[4];
    if ((threadIdx.x & 63) == 0) wmax[threadIdx.x >> 6] = m;
    __syncthreads();
    if (threadIdx.x == 0)
        partial[blockIdx.x] = fmaxf(fmaxf(wmax[0], wmax[1]), fmaxf(wmax[2], wmax[3]));
}

__global__ void maxreduce_kernel(const float* __restrict__ partial, float* __restrict__ kstab) {
    float m = partial[threadIdx.x];
    for (int o = 32; o > 0; o >>= 1) m = fmaxf(m, __shfl_down(m, o));
    if (threadIdx.x == 0) kstab[0] = m;
}

// ---------------- random feature maps -> bf16 [h][n][MPAD], zero tail ----------------
__global__ __launch_bounds__(256) void feat_kernel(const float* __restrict__ xh,
                                                   const float* __restrict__ rf,
                                                   const float* __restrict__ hkv,
                                                   const float* __restrict__ kstab,
                                                   short* __restrict__ outp, int isQ) {
    int mt = blockIdx.x, nt = blockIdx.y, h = blockIdx.z;
    int n0 = nt * 64, m0 = mt * 64;
    int tid = threadIdx.x;
    int tx = tid & 15, ty = tid >> 4;
    __shared__ float Xs[64][68];  // [d][n]
    __shared__ float Rs[64][68];  // [d][m]
    for (int l = 0; l < 4; ++l) {
        int idx = tid + l * 256;
        int nloc = idx >> 4, dq = idx & 15;
        f32x4 v = *(const f32x4*)&xh[(size_t)(n0 + nloc) * DMODEL + h * DK + dq * 4];
        for (int j = 0; j < 4; ++j) Xs[dq * 4 + j][nloc] = v[j];
        int mloc = nloc;
        int m = m0 + mloc;
        f32x4 rv = {0.f, 0.f, 0.f, 0.f};
        if (m < MFEAT) rv = *(const f32x4*)&rf[(size_t)m * DK + dq * 4];
        for (int j = 0; j < 4; ++j) Rs[dq * 4 + j][mloc] = rv[j];
    }
    __syncthreads();
    float acc[4][4] = {};
#pragma unroll 4
    for (int d = 0; d < 64; ++d) {
        f32x4 a = *(const f32x4*)&Xs[d][ty * 4];
        f32x4 b = *(const f32x4*)&Rs[d][tx * 4];
        for (int r = 0; r < 4; ++r)
            for (int c = 0; c < 4; ++c) acc[r][c] += a[r] * b[c];
    }
    const float cnorm = 0.06131393394849658f;  // 266^-0.5
    float ks = kstab[0];
    if (m0 + tx * 4 + 3 < MPAD) {
        for (int r = 0; r < 4; ++r) {
            int n = n0 + ty * 4 + r;
            float hval = isQ ? 0.f : hkv[(size_t)h * NSEQ + n] - ks;
            sv4 o;
            for (int c = 0; c < 4; ++c) {
                int mg = m0 + tx * 4 + c;
                float val = (mg < MFEAT) ? cnorm * (expf(acc[r][c] + hval) + KERNEL_EPS) : 0.f;
                o[c] = f2bf(val);
            }
            *(sv4*)&outp[((size_t)h * NSEQ + n) * MPAD + m0 + tx * 4] = o;
        }
    }
}

// ---------------- phase A: per-chunk sums, transposed KVt[(h,t,dv)][m], Ks[(h,t)][m] ----------------
__global__ __launch_bounds__(256) void chunksum_kernel(const short* __restrict__ kp,
                                                       const float* __restrict__ vh,
                                                       float* __restrict__ KVt,
                                                       float* __restrict__ Ks) {
    int mt = blockIdx.x, t = blockIdx.y, h = blockIdx.z;
    int m0 = mt * 64;
    int tid = threadIdx.x;
    int tx = tid & 15, ty = tid >> 4;
    __shared__ float Kl[64][68];  // [i][mloc]
    __shared__ float Vl[64][68];  // [i][dv]
    for (int l = 0; l < 2; ++l) {
        int idx = tid + l * 256;
        int i = idx >> 3, c8 = idx & 7;
        int m = m0 + c8 * 8;
        float vals[8] = {0.f, 0.f, 0.f, 0.f, 0.f, 0.f, 0.f, 0.f};
        if (m + 7 < MPAD) {
            short8 sv = *(const short8*)&kp[((size_t)h * NSEQ + t * 64 + i) * MPAD + m];
            for (int j = 0; j < 8; ++j) vals[j] = bf2f(sv[j]);
        }
        for (int j = 0; j < 8; ++j) Kl[i][c8 * 8 + j] = vals[j];
    }
    for (int l = 0; l < 4; ++l) {
        int idx = tid + l * 256;
        int i = idx >> 4, q4 = idx & 15;
        f32x4 vv = *(const f32x4*)&vh[(size_t)(t * 64 + i) * DMODEL + h * DV + q4 * 4];
        *(f32x4*)&Vl[i][q4 * 4] = vv;
    }
    __syncthreads();
    float acc[4][4] = {};
#pragma unroll 4
    for (int i = 0; i < 64; ++i) {
        f32x4 a = *(const f32x4*)&Kl[i][ty * 4];
        f32x4 b = *(const f32x4*)&Vl[i][tx * 4];
        for (int r = 0; r < 4; ++r)
            for (int c = 0; c < 4; ++c) acc[r][c] += a[r] * b[c];
    }
    int m = m0 + ty * 4;
    if (m < MPAD) {
        for (int c = 0; c < 4; ++c) {
            int dv = tx * 4 + c;
            f32x4 o = {acc[0][c], acc[1][c], acc[2][c], acc[3][c]};
            *(f32x4*)&KVt[(((size_t)h * NT + t) * DV + dv) * MPAD + m] = o;
        }
    }
    if (tid < 64) {
        int ms = m0 + tid;
        if (ms < MPAD) {
            float s = 0.f;
#pragma unroll 8
            for (int i = 0; i < 64; ++i) s += Kl[i][tid];
            Ks[((size_t)h * NT + t) * MPAD + ms] = s;
        }
    }
}

// ---------------- exclusive chunk-scan, coalesced, emits bf16 S^T ----------------
__global__ void scank_kernel(const float* __restrict__ KVt, short* __restrict__ KVbT) {
    int idx = blockIdx.x * 256 + threadIdx.x;  // < 8*64*288
    if (idx >= NHEAD * DV * MPAD) return;
    int h = idx / (DV * MPAD);
    int rem = idx % (DV * MPAD);
    size_t base = (size_t)h * NT * DV * MPAD + rem;
    float run = 0.f;
    for (int t = 0; t < NT; ++t) {
        size_t o = base + (size_t)t * DV * MPAD;
        KVbT[o] = f2bf(run);
        run += KVt[o];
    }
}

__global__ void scanks_kernel(float* __restrict__ Ks, float* __restrict__ Ktot) {
    int idx = blockIdx.x * 256 + threadIdx.x;
    if (idx >= NHEAD * MPAD) return;
    int h = idx / MPAD, m = idx % MPAD;
    size_t base = (size_t)h * NT * MPAD + m;
    float run = 0.f;
    for (int t = 0; t < NT; ++t) {
        size_t o = base + (size_t)t * MPAD;
        float v = Ks[o];
        Ks[o] = run;
        run += v;
    }
    Ktot[(size_t)h * MPAD + m] = run;
}

// ---------------- phase C: MFMA intra+inter+denominators ----------------
__global__ __launch_bounds__(256) void phasec_kernel(const short* __restrict__ qp,
                                                     const short* __restrict__ kp,
                                                     const float* __restrict__ vh,
                                                     const short* __restrict__ KVbT,
                                                     const float* __restrict__ Ks,
                                                     const float* __restrict__ Ktot,
                                                     float* __restrict__ attn) {
    int t = blockIdx.x, h = blockIdx.y;
    __shared__ short Buf[64][296];   // Kp (QK^T phase) then St (inter phase)
    __shared__ short Vt[64][72];     // [dv][i]
    __shared__ short Am[64][72];     // masked A, bf16
    __shared__ float Ksp[MPAD], Ktp[MPAD];
    __shared__ float fscale_s[64];
    int tid = threadIdx.x;
    int w = tid >> 6, l = tid & 63;
    int fr = l & 15, fq = (l >> 4) * 8;
    const short* qpb = qp + ((size_t)h * NSEQ + (size_t)t * 64) * MPAD;
    const short* kpb = kp + ((size_t)h * NSEQ + (size_t)t * 64) * MPAD;
    const short* stb = KVbT + ((size_t)h * NT + t) * DV * MPAD;

    // Q-fragments in registers: rows w*16+fr, all K
    short8 qf[9];
#pragma unroll
    for (int ks = 0; ks < 9; ++ks)
        qf[ks] = *(const short8*)&qpb[(size_t)(w * 16 + fr) * MPAD + ks * 32 + fq];

    // stage Kp into Buf
    int srow = tid >> 2, sc4 = tid & 3;
#pragma unroll
    for (int lp = 0; lp < 9; ++lp) {
        int c = sc4 + lp * 4;
        *(short8*)&Buf[srow][c * 8] = *(const short8*)&kpb[(size_t)srow * MPAD + c * 8];
    }
    // stage Vt transposed (bf16)
    {
        int dv = tid >> 2, iq = (tid & 3) * 16;
        short8 v0, v1;
        for (int it = 0; it < 8; ++it)
            v0[it] = f2bf(vh[(size_t)(t * 64 + iq + it) * DMODEL + h * DV + dv]);
        for (int it = 0; it < 8; ++it)
            v1[it] = f2bf(vh[(size_t)(t * 64 + iq + 8 + it) * DMODEL + h * DV + dv]);
        *(short8*)&Vt[dv][iq] = v0;
        *(short8*)&Vt[dv][iq + 8] = v1;
    }
    // stage Ks_prev / Ktot
    for (int idx = tid; idx < MPAD; idx += 256) {
        Ksp[idx] = Ks[((size_t)h * NT + t) * MPAD + idx];
        Ktp[idx] = Ktot[(size_t)h * MPAD + idx];
    }
    __syncthreads();

    f32x4 accA[4] = {f32x4{0,0,0,0}, f32x4{0,0,0,0}, f32x4{0,0,0,0}, f32x4{0,0,0,0}};
    f32x4 accO[4] = {f32x4{0,0,0,0}, f32x4{0,0,0,0}, f32x4{0,0,0,0}, f32x4{0,0,0,0}};
    // A = Qp . Kp^T
#pragma unroll 3
    for (int ks = 0; ks < 9; ++ks) {
        int ko = ks * 32 + fq;
        for (int nf = 0; nf < 4; ++nf) {
            short8 bk = *(const short8*)&Buf[nf * 16 + fr][ko];
            accA[nf] = __builtin_amdgcn_mfma_f32_16x16x32_bf16(qf[ks], bk, accA[nf], 0, 0, 0);
        }
    }
    __syncthreads();
    // overwrite Buf with St; write masked Am
#pragma unroll
    for (int lp = 0; lp < 9; ++lp) {
        int c = sc4 + lp * 4;
        *(short8*)&Buf[srow][c * 8] = *(const short8*)&stb[(size_t)srow * MPAD + c * 8];
    }
    for (int nf = 0; nf < 4; ++nf) {
        int col = nf * 16 + fr;
        for (int j = 0; j < 4; ++j) {
            int row = w * 16 + (l >> 4) * 4 + j;
            Am[row][col] = (col <= row) ? f2bf(accA[nf][j]) : (short)0;
        }
    }
    __syncthreads();
    // inter: accO += Qp . S
#pragma unroll 3
    for (int ks = 0; ks < 9; ++ks) {
        int ko = ks * 32 + fq;
        for (int nf = 0; nf < 4; ++nf) {
            short8 bs = *(const short8*)&Buf[nf * 16 + fr][ko];
            accO[nf] = __builtin_amdgcn_mfma_f32_16x16x32_bf16(qf[ks], bs, accO[nf], 0, 0, 0);
        }
    }
    // intra: accO += Am_masked . V
#pragma unroll
    for (int ks = 0; ks < 2; ++ks) {
        int ko = ks * 32 + fq;
        short8 a = *(const short8*)&Am[w * 16 + fr][ko];
        for (int nf = 0; nf < 4; ++nf) {
            short8 b = *(const short8*)&Vt[nf * 16 + fr][ko];
            accO[nf] = __builtin_amdgcn_mfma_f32_16x16x32_bf16(a, b, accO[nf], 0, 0, 0);
        }
    }
    // denominators: row di, partial dp
    int di = tid >> 2, dp = tid & 3;
    float dc = 0.f, df = 0.f;
    {
        const short* amrow = &Am[di][dp * 16];
        short8 s0 = *(const short8*)amrow;
        short8 s1 = *(const short8*)(amrow + 8);
        for (int j2 = 0; j2 < 8; ++j2) dc += bf2f(s0[j2]) + bf2f(s1[j2]);
    }
#pragma unroll
    for (int c8 = 0; c8 < 9; ++c8) {
        int m = dp * 72 + c8 * 8;
        short8 qv = *(const short8*)&qpb[(size_t)di * MPAD + m];
        for (int j2 = 0; j2 < 8; ++j2) {
            float qq = bf2f(qv[j2]);
            dc += qq * Ksp[m + j2];
            df += qq * Ktp[m + j2];
        }
    }
    dc += __shfl_xor(dc, 1); dc += __shfl_xor(dc, 2);
    df += __shfl_xor(df, 1); df += __shfl_xor(df, 2);
    if (dp == 0) {
        float dst = df;
        if (fabsf(dst) <= NORM_STAB) dst += 2.f * NORM_STAB;
        fscale_s[di] = (1.f / dc) / dst;
    }
    __syncthreads();
    // epilogue
    for (int nf = 0; nf < 4; ++nf) {
        int col = nf * 16 + fr;
        for (int j = 0; j < 4; ++j) {
            int row = w * 16 + (l >> 4) * 4 + j;
            attn[((size_t)t * 64 + row) * DMODEL + h * DV + col] = accO[nf][j] * fscale_s[row];
        }
    }
}

extern "C" void kernel_launch(void* const* d_in, const int* in_sizes, int n_in,
                              void* d_out, int out_size, void* d_ws, size_t ws_size,
                              hipStream_t stream) {
    const float* q = (const float*)d_in[0];
    const float* k = (const float*)d_in[1];
    const float* v = (const float*)d_in[2];
    const float* Wq = (const float*)d_in[3];
    const float* Wk = (const float*)d_in[4];
    const float* Wv = (const float*)d_in[5];
    const float* Wfc = (const float*)d_in[6];
    const float* bfc = (const float*)d_in[7];
    const float* gamma = (const float*)d_in[8];
    const float* beta = (const float*)d_in[9];
    const float* rf = (const float*)d_in[10];
    float* out = (float*)d_out;

    float* ws = (float*)d_ws;
    float* qn = ws;                                        // 2048*512 (reused as attn out)
    float* qh = qn + (size_t)NSEQ * DMODEL;                // 2048*512
    float* kh = qh + (size_t)NSEQ * DMODEL;                // 2048*512
    float* vhb = kh + (size_t)NSEQ * DMODEL;               // 2048*512
    short* qp = (short*)(vhb + (size_t)NSEQ * DMODEL);     // bf16 8*2048*288
    short* kp = qp + (size_t)NHEAD * NSEQ * MPAD;          // bf16 8*2048*288
    float* KVt = (float*)(kp + (size_t)NHEAD * NSEQ * MPAD);   // 8*32*64*288 fp32
    short* KVbT = (short*)(KVt + (size_t)NHEAD * NT * DV * MPAD);  // bf16 same extent
    float* Ks = (float*)(KVbT + (size_t)NHEAD * NT * DV * MPAD);   // 8*32*288
    float* Ktot = Ks + (size_t)NHEAD * NT * MPAD;          // 8*288
    float* hk = Ktot + (size_t)NHEAD * MPAD;               // 8*2048
    float* partial = hk + (size_t)NHEAD * NSEQ;            // 64
    float* kstab = partial + 64;                           // 4

    const float scale = 0.21022410381342863f;  // 512^-0.25

    ln_kernel<<<NSEQ, 256, 0, stream>>>(q, gamma, beta, qn);
    dim3 g(DMODEL / 64, NSEQ / 64);
    mgemm_kernel<<<g, 256, 0, stream>>>(qn, Wq, qh, NSEQ, DMODEL, DMODEL, scale, nullptr, nullptr);
    mgemm_kernel<<<g, 256, 0, stream>>>(k, Wk, kh, NSEQ, DMODEL, DMODEL, scale, nullptr, nullptr);
    mgemm_kernel<<<g, 256, 0, stream>>>(v, Wv, vhb, NSEQ, DMODEL, DMODEL, 1.f, nullptr, nullptr);
    hk_kernel<<<64, 256, 0, stream>>>(kh, hk, partial);
    maxreduce_kernel<<<1, 64, 0, stream>>>(partial, kstab);
    dim3 gf(5, NSEQ / 64, NHEAD);
    feat_kernel<<<gf, 256, 0, stream>>>(qh, rf, hk, kstab, qp, 1);
    feat_kernel<<<gf, 256, 0, stream>>>(kh, rf, hk, kstab, kp, 0);
    dim3 ga(5, NT, NHEAD);
    chunksum_kernel<<<ga, 256, 0, stream>>>(kp, vhb, KVt, Ks);
    scank_kernel<<<(NHEAD * DV * MPAD + 255) / 256, 256, 0, stream>>>(KVt, KVbT);
    scanks_kernel<<<(NHEAD * MPAD + 255) / 256, 256, 0, stream>>>(Ks, Ktot);
    dim3 gc(NT, NHEAD);
    phasec_kernel<<<gc, 256, 0, stream>>>(qp, kp, vhb, KVbT, Ks, Ktot, qn);
    mgemm_kernel<<<g, 256, 0, stream>>>(qn, Wfc, out, NSEQ, DMODEL, DMODEL, 1.f, bfc, q);
}

// Round 6
// 129.341 us; speedup vs baseline: 13.9914x; 1.3740x over previous
//
#include <hip/hip_runtime.h>
#include <math.h>

#define DMODEL 512
#define NSEQ 2048
#define NHEAD 8
#define DK 64
#define DV 64
#define MFEAT 266
#define MPAD 288        // padded feature dim for bf16 MFMA (zero tail), mult of 32
#define NT 32           // number of chunks (chunk = 64)
#define LN_EPS 1e-6f
#define KERNEL_EPS 1e-4f
#define NORM_STAB 1e-6f
#define SCALE 0.21022410381342863f  // 512^-0.25

typedef __attribute__((ext_vector_type(8))) short short8;
typedef __attribute__((ext_vector_type(4))) short sv4;
typedef __attribute__((ext_vector_type(4))) float f32x4;

__device__ inline short f2bf(float f) {
    unsigned u = __builtin_bit_cast(unsigned, f);
    unsigned r = (u + 0x7fff + ((u >> 16) & 1)) >> 16;
    return (short)r;
}
__device__ inline float bf2f(short s) {
    unsigned u = ((unsigned)(unsigned short)s) << 16;
    return __builtin_bit_cast(float, u);
}

// ---------------- LayerNorm on q (fp32 out) ----------------
__global__ __launch_bounds__(256) void ln_kernel(const float* __restrict__ q,
                                                 const float* __restrict__ gamma,
                                                 const float* __restrict__ beta,
                                                 float* __restrict__ qn) {
    int row = blockIdx.x;
    int tid = threadIdx.x;
    const float* x = q + (size_t)row * DMODEL;
    float x0 = x[tid], x1 = x[tid + 256];
    float s = x0 + x1, ss = x0 * x0 + x1 * x1;
    for (int o = 32; o > 0; o >>= 1) {
        s += __shfl_down(s, o);
        ss += __shfl_down(ss, o);
    }
    __shared__ float sbuf[4], ssbuf[4];
    __shared__ float mu_s, rstd_s;
    int wid = tid >> 6, lane = tid & 63;
    if (lane == 0) { sbuf[wid] = s; ssbuf[wid] = ss; }
    __syncthreads();
    if (tid == 0) {
        float st = sbuf[0] + sbuf[1] + sbuf[2] + sbuf[3];
        float sst = ssbuf[0] + ssbuf[1] + ssbuf[2] + ssbuf[3];
        float mu = st / (float)DMODEL;
        float var = sst / (float)DMODEL - mu * mu;
        mu_s = mu;
        rstd_s = rsqrtf(var + LN_EPS);
    }
    __syncthreads();
    float mu = mu_s, rstd = rstd_s;
    qn[(size_t)row * DMODEL + tid] = (x0 - mu) * rstd * gamma[tid] + beta[tid];
    qn[(size_t)row * DMODEL + tid + 256] = (x1 - mu) * rstd * gamma[tid + 256] + beta[tid + 256];
}

// ---------------- fused QKV bf16 MFMA GEMM (z selects Q/K/V); K-path emits h_k + max partials ----------------
__global__ __launch_bounds__(256) void qkv_kernel(const float* __restrict__ qn,
                                                  const float* __restrict__ kx,
                                                  const float* __restrict__ vx,
                                                  const float* __restrict__ Wq,
                                                  const float* __restrict__ Wk,
                                                  const float* __restrict__ Wv,
                                                  float* __restrict__ qh,
                                                  float* __restrict__ kh,
                                                  float* __restrict__ vh,
                                                  float* __restrict__ hk,
                                                  float* __restrict__ partial) {
    int z = blockIdx.z;
    const float* A = (z == 0) ? qn : (z == 1) ? kx : vx;
    const float* B = (z == 0) ? Wq : (z == 1) ? Wk : Wv;
    float* C = (z == 0) ? qh : (z == 1) ? kh : vh;
    float scale = (z == 2) ? 1.f : SCALE;

    __shared__ short As[64][40];
    __shared__ short Bs[64][40];
    int bm = blockIdx.y * 64, bn = blockIdx.x * 64;
    int tid = threadIdx.x;
    int wid = tid >> 6, lane = tid & 63;
    f32x4 acc[4] = {f32x4{0,0,0,0}, f32x4{0,0,0,0}, f32x4{0,0,0,0}, f32x4{0,0,0,0}};
    int ar = tid >> 2, akq = tid & 3;
    int bkk = tid >> 3, bng = tid & 7;
    for (int k0 = 0; k0 < DMODEL; k0 += 32) {
        {
            const float* src = A + (size_t)(bm + ar) * DMODEL + k0 + akq * 8;
            f32x4 v0 = *(const f32x4*)src;
            f32x4 v1 = *(const f32x4*)(src + 4);
            short8 sv;
            for (int j = 0; j < 4; ++j) { sv[j] = f2bf(v0[j]); sv[4 + j] = f2bf(v1[j]); }
            *(short8*)&As[ar][akq * 8] = sv;
        }
        {
            const float* src = B + (size_t)(k0 + bkk) * DMODEL + bn + bng * 8;
            f32x4 v0 = *(const f32x4*)src;
            f32x4 v1 = *(const f32x4*)(src + 4);
            for (int j = 0; j < 4; ++j) {
                Bs[bng * 8 + j][bkk] = f2bf(v0[j] * scale);
                Bs[bng * 8 + 4 + j][bkk] = f2bf(v1[j] * scale);
            }
        }
        __syncthreads();
        int row = wid * 16 + (lane & 15);
        int koff = (lane >> 4) * 8;
        short8 a = *(const short8*)&As[row][koff];
        for (int nf = 0; nf < 4; ++nf) {
            int col = nf * 16 + (lane & 15);
            short8 b = *(const short8*)&Bs[col][koff];
            acc[nf] = __builtin_amdgcn_mfma_f32_16x16x32_bf16(a, b, acc[nf], 0, 0, 0);
        }
        __syncthreads();
    }
    for (int nf = 0; nf < 4; ++nf) {
        int col = bn + nf * 16 + (lane & 15);
        for (int j = 0; j < 4; ++j) {
            int row = bm + wid * 16 + (lane >> 4) * 4 + j;
            C[(size_t)row * DMODEL + col] = acc[nf][j];
        }
    }
    if (z == 1) {
        // h_k = -0.5 * ||kh_row||^2 for this head (head == blockIdx.x since DK==64)
        __shared__ float bmax[4];
        float hvmax = -1e30f;
        for (int j = 0; j < 4; ++j) {
            float ss = 0.f;
            for (int nf = 0; nf < 4; ++nf) ss += acc[nf][j] * acc[nf][j];
            for (int o = 1; o < 16; o <<= 1) ss += __shfl_xor(ss, o);
            float hv = -0.5f * ss;
            int row = bm + wid * 16 + (lane >> 4) * 4 + j;
            if ((lane & 15) == 0) hk[(size_t)blockIdx.x * NSEQ + row] = hv;
            hvmax = fmaxf(hvmax, hv);
        }
        for (int o = 32; o > 0; o >>= 1) hvmax = fmaxf(hvmax, __shfl_down(hvmax, o));
        if (lane == 0) bmax[wid] = hvmax;
        __syncthreads();
        if (tid == 0)
            partial[blockIdx.y * 8 + blockIdx.x] =
                fmaxf(fmaxf(bmax[0], bmax[1]), fmaxf(bmax[2], bmax[3]));
    }
}

__global__ void maxreduce_kernel(const float* __restrict__ partial, float* __restrict__ kstab) {
    int tid = threadIdx.x;  // 256 threads, 256 partials
    float m = partial[tid];
    for (int o = 32; o > 0; o >>= 1) m = fmaxf(m, __shfl_down(m, o));
    __shared__ float w[4];
    if ((tid & 63) == 0) w[tid >> 6] = m;
    __syncthreads();
    if (tid == 0) kstab[0] = fmaxf(fmaxf(w[0], w[1]), fmaxf(w[2], w[3]));
}

// ---------------- fused random feature maps -> bf16 [h][n][MPAD]; z = h + 8*isQ ----------------
__global__ __launch_bounds__(256) void feat_kernel(const float* __restrict__ qh,
                                                   const float* __restrict__ kh,
                                                   const float* __restrict__ rf,
                                                   const float* __restrict__ hkv,
                                                   const float* __restrict__ kstab,
                                                   short* __restrict__ qp,
                                                   short* __restrict__ kp) {
    int mt = blockIdx.x, nt = blockIdx.y;
    int h = blockIdx.z & 7, isQ = blockIdx.z >> 3;
    const float* xh = isQ ? qh : kh;
    short* outp = isQ ? qp : kp;
    int n0 = nt * 64, m0 = mt * 64;
    int tid = threadIdx.x;
    int tx = tid & 15, ty = tid >> 4;
    __shared__ float Xs[64][68];  // [d][n]
    __shared__ float Rs[64][68];  // [d][m]
    for (int l = 0; l < 4; ++l) {
        int idx = tid + l * 256;
        int nloc = idx >> 4, dq = idx & 15;
        f32x4 v = *(const f32x4*)&xh[(size_t)(n0 + nloc) * DMODEL + h * DK + dq * 4];
        for (int j = 0; j < 4; ++j) Xs[dq * 4 + j][nloc] = v[j];
        int mloc = nloc;
        int m = m0 + mloc;
        f32x4 rv = {0.f, 0.f, 0.f, 0.f};
        if (m < MFEAT) rv = *(const f32x4*)&rf[(size_t)m * DK + dq * 4];
        for (int j = 0; j < 4; ++j) Rs[dq * 4 + j][mloc] = rv[j];
    }
    __syncthreads();
    float acc[4][4] = {};
#pragma unroll 4
    for (int d = 0; d < 64; ++d) {
        f32x4 a = *(const f32x4*)&Xs[d][ty * 4];
        f32x4 b = *(const f32x4*)&Rs[d][tx * 4];
        for (int r = 0; r < 4; ++r)
            for (int c = 0; c < 4; ++c) acc[r][c] += a[r] * b[c];
    }
    const float cnorm = 0.06131393394849658f;  // 266^-0.5
    float ks = kstab[0];
    if (m0 + tx * 4 + 3 < MPAD) {
        for (int r = 0; r < 4; ++r) {
            int n = n0 + ty * 4 + r;
            float hval = isQ ? 0.f : hkv[(size_t)h * NSEQ + n] - ks;
            sv4 o;
            for (int c = 0; c < 4; ++c) {
                int mg = m0 + tx * 4 + c;
                float val = (mg < MFEAT) ? cnorm * (expf(acc[r][c] + hval) + KERNEL_EPS) : 0.f;
                o[c] = f2bf(val);
            }
            *(sv4*)&outp[((size_t)h * NSEQ + n) * MPAD + m0 + tx * 4] = o;
        }
    }
}

// ---------------- phase A: per-chunk sums, transposed KVt[(h,t,dv)][m], Ks[(h,t)][m] ----------------
__global__ __launch_bounds__(256) void chunksum_kernel(const short* __restrict__ kp,
                                                       const float* __restrict__ vh,
                                                       float* __restrict__ KVt,
                                                       float* __restrict__ Ks) {
    int mt = blockIdx.x, t = blockIdx.y, h = blockIdx.z;
    int m0 = mt * 64;
    int tid = threadIdx.x;
    int tx = tid & 15, ty = tid >> 4;
    __shared__ float Kl[64][68];  // [i][mloc]
    __shared__ float Vl[64][68];  // [i][dv]
    for (int l = 0; l < 2; ++l) {
        int idx = tid + l * 256;
        int i = idx >> 3, c8 = idx & 7;
        int m = m0 + c8 * 8;
        float vals[8] = {0.f, 0.f, 0.f, 0.f, 0.f, 0.f, 0.f, 0.f};
        if (m + 7 < MPAD) {
            short8 sv = *(const short8*)&kp[((size_t)h * NSEQ + t * 64 + i) * MPAD + m];
            for (int j = 0; j < 8; ++j) vals[j] = bf2f(sv[j]);
        }
        for (int j = 0; j < 8; ++j) Kl[i][c8 * 8 + j] = vals[j];
    }
    for (int l = 0; l < 4; ++l) {
        int idx = tid + l * 256;
        int i = idx >> 4, q4 = idx & 15;
        f32x4 vv = *(const f32x4*)&vh[(size_t)(t * 64 + i) * DMODEL + h * DV + q4 * 4];
        *(f32x4*)&Vl[i][q4 * 4] = vv;
    }
    __syncthreads();
    float acc[4][4] = {};
#pragma unroll 4
    for (int i = 0; i < 64; ++i) {
        f32x4 a = *(const f32x4*)&Kl[i][ty * 4];
        f32x4 b = *(const f32x4*)&Vl[i][tx * 4];
        for (int r = 0; r < 4; ++r)
            for (int c = 0; c < 4; ++c) acc[r][c] += a[r] * b[c];
    }
    int m = m0 + ty * 4;
    if (m < MPAD) {
        for (int c = 0; c < 4; ++c) {
            int dv = tx * 4 + c;
            f32x4 o = {acc[0][c], acc[1][c], acc[2][c], acc[3][c]};
            *(f32x4*)&KVt[(((size_t)h * NT + t) * DV + dv) * MPAD + m] = o;
        }
    }
    if (tid < 64) {
        int ms = m0 + tid;
        if (ms < MPAD) {
            float s = 0.f;
#pragma unroll 8
            for (int i = 0; i < 64; ++i) s += Kl[i][tid];
            Ks[((size_t)h * NT + t) * MPAD + ms] = s;
        }
    }
}

// ---------------- fused exclusive chunk-scans (KV -> bf16 S^T, Ks -> prefix + Ktot) ----------------
__global__ void scan_kernel(const float* __restrict__ KVt, short* __restrict__ KVbT,
                            float* __restrict__ Ks, float* __restrict__ Ktot) {
    int idx = blockIdx.x * 256 + threadIdx.x;
    const int NKV = NHEAD * DV * MPAD;       // 147456
    if (idx < NKV) {
        int h = idx / (DV * MPAD);
        int rem = idx % (DV * MPAD);
        size_t base = (size_t)h * NT * DV * MPAD + rem;
        float run = 0.f;
        for (int t = 0; t < NT; ++t) {
            size_t o = base + (size_t)t * DV * MPAD;
            KVbT[o] = f2bf(run);
            run += KVt[o];
        }
    } else {
        int j = idx - NKV;
        if (j < NHEAD * MPAD) {
            int h = j / MPAD, m = j % MPAD;
            size_t base = (size_t)h * NT * MPAD + m;
            float run = 0.f;
            for (int t = 0; t < NT; ++t) {
                size_t o = base + (size_t)t * MPAD;
                float v = Ks[o];
                Ks[o] = run;
                run += v;
            }
            Ktot[(size_t)h * MPAD + m] = run;
        }
    }
}

// ---------------- phase C: MFMA intra+inter+denominators ----------------
__global__ __launch_bounds__(256) void phasec_kernel(const short* __restrict__ qp,
                                                     const short* __restrict__ kp,
                                                     const float* __restrict__ vh,
                                                     const short* __restrict__ KVbT,
                                                     const float* __restrict__ Ks,
                                                     const float* __restrict__ Ktot,
                                                     float* __restrict__ attn) {
    int t = blockIdx.x, h = blockIdx.y;
    __shared__ short Buf[64][296];   // Kp (QK^T phase) then St (inter phase)
    __shared__ short Vt[64][72];     // [dv][i]
    __shared__ short Am[64][72];     // masked A, bf16
    __shared__ float Ksp[MPAD], Ktp[MPAD];
    __shared__ float fscale_s[64];
    int tid = threadIdx.x;
    int w = tid >> 6, l = tid & 63;
    int fr = l & 15, fq = (l >> 4) * 8;
    const short* qpb = qp + ((size_t)h * NSEQ + (size_t)t * 64) * MPAD;
    const short* kpb = kp + ((size_t)h * NSEQ + (size_t)t * 64) * MPAD;
    const short* stb = KVbT + ((size_t)h * NT + t) * DV * MPAD;

    short8 qf[9];
#pragma unroll
    for (int ks = 0; ks < 9; ++ks)
        qf[ks] = *(const short8*)&qpb[(size_t)(w * 16 + fr) * MPAD + ks * 32 + fq];

    int srow = tid >> 2, sc4 = tid & 3;
#pragma unroll
    for (int lp = 0; lp < 9; ++lp) {
        int c = sc4 + lp * 4;
        *(short8*)&Buf[srow][c * 8] = *(const short8*)&kpb[(size_t)srow * MPAD + c * 8];
    }
    {
        int dv = tid >> 2, iq = (tid & 3) * 16;
        short8 v0, v1;
        for (int it = 0; it < 8; ++it)
            v0[it] = f2bf(vh[(size_t)(t * 64 + iq + it) * DMODEL + h * DV + dv]);
        for (int it = 0; it < 8; ++it)
            v1[it] = f2bf(vh[(size_t)(t * 64 + iq + 8 + it) * DMODEL + h * DV + dv]);
        *(short8*)&Vt[dv][iq] = v0;
        *(short8*)&Vt[dv][iq + 8] = v1;
    }
    for (int idx = tid; idx < MPAD; idx += 256) {
        Ksp[idx] = Ks[((size_t)h * NT + t) * MPAD + idx];
        Ktp[idx] = Ktot[(size_t)h * MPAD + idx];
    }
    __syncthreads();

    f32x4 accA[4] = {f32x4{0,0,0,0}, f32x4{0,0,0,0}, f32x4{0,0,0,0}, f32x4{0,0,0,0}};
    f32x4 accO[4] = {f32x4{0,0,0,0}, f32x4{0,0,0,0}, f32x4{0,0,0,0}, f32x4{0,0,0,0}};
#pragma unroll 3
    for (int ks = 0; ks < 9; ++ks) {
        int ko = ks * 32 + fq;
        for (int nf = 0; nf < 4; ++nf) {
            short8 bk = *(const short8*)&Buf[nf * 16 + fr][ko];
            accA[nf] = __builtin_amdgcn_mfma_f32_16x16x32_bf16(qf[ks], bk, accA[nf], 0, 0, 0);
        }
    }
    __syncthreads();
#pragma unroll
    for (int lp = 0; lp < 9; ++lp) {
        int c = sc4 + lp * 4;
        *(short8*)&Buf[srow][c * 8] = *(const short8*)&stb[(size_t)srow * MPAD + c * 8];
    }
    for (int nf = 0; nf < 4; ++nf) {
        int col = nf * 16 + fr;
        for (int j = 0; j < 4; ++j) {
            int row = w * 16 + (l >> 4) * 4 + j;
            Am[row][col] = (col <= row) ? f2bf(accA[nf][j]) : (short)0;
        }
    }
    __syncthreads();
#pragma unroll 3
    for (int ks = 0; ks < 9; ++ks) {
        int ko = ks * 32 + fq;
        for (int nf = 0; nf < 4; ++nf) {
            short8 bs = *(const short8*)&Buf[nf * 16 + fr][ko];
            accO[nf] = __builtin_amdgcn_mfma_f32_16x16x32_bf16(qf[ks], bs, accO[nf], 0, 0, 0);
        }
    }
#pragma unroll
    for (int ks = 0; ks < 2; ++ks) {
        int ko = ks * 32 + fq;
        short8 a = *(const short8*)&Am[w * 16 + fr][ko];
        for (int nf = 0; nf < 4; ++nf) {
            short8 b = *(const short8*)&Vt[nf * 16 + fr][ko];
            accO[nf] = __builtin_amdgcn_mfma_f32_16x16x32_bf16(a, b, accO[nf], 0, 0, 0);
        }
    }
    int di = tid >> 2, dp = tid & 3;
    float dc = 0.f, df = 0.f;
    {
        const short* amrow = &Am[di][dp * 16];
        short8 s0 = *(const short8*)amrow;
        short8 s1 = *(const short8*)(amrow + 8);
        for (int j2 = 0; j2 < 8; ++j2) dc += bf2f(s0[j2]) + bf2f(s1[j2]);
    }
#pragma unroll
    for (int c8 = 0; c8 < 9; ++c8) {
        int m = dp * 72 + c8 * 8;
        short8 qv = *(const short8*)&qpb[(size_t)di * MPAD + m];
        for (int j2 = 0; j2 < 8; ++j2) {
            float qq = bf2f(qv[j2]);
            dc += qq * Ksp[m + j2];
            df += qq * Ktp[m + j2];
        }
    }
    dc += __shfl_xor(dc, 1); dc += __shfl_xor(dc, 2);
    df += __shfl_xor(df, 1); df += __shfl_xor(df, 2);
    if (dp == 0) {
        float dst = df;
        if (fabsf(dst) <= NORM_STAB) dst += 2.f * NORM_STAB;
        fscale_s[di] = (1.f / dc) / dst;
    }
    __syncthreads();
    for (int nf = 0; nf < 4; ++nf) {
        int col = nf * 16 + fr;
        for (int j = 0; j < 4; ++j) {
            int row = w * 16 + (l >> 4) * 4 + j;
            attn[((size_t)t * 64 + row) * DMODEL + h * DV + col] = accO[nf][j] * fscale_s[row];
        }
    }
}

// ---------------- final GEMM with bias + residual ----------------
__global__ __launch_bounds__(256) void fgemm_kernel(const float* __restrict__ A,
                                                    const float* __restrict__ B,
                                                    float* __restrict__ C,
                                                    const float* __restrict__ bias,
                                                    const float* __restrict__ residual) {
    __shared__ short As[64][40];
    __shared__ short Bs[64][40];
    int bm = blockIdx.y * 64, bn = blockIdx.x * 64;
    int tid = threadIdx.x;
    int wid = tid >> 6, lane = tid & 63;
    f32x4 acc[4] = {f32x4{0,0,0,0}, f32x4{0,0,0,0}, f32x4{0,0,0,0}, f32x4{0,0,0,0}};
    int ar = tid >> 2, akq = tid & 3;
    int bkk = tid >> 3, bng = tid & 7;
    for (int k0 = 0; k0 < DMODEL; k0 += 32) {
        {
            const float* src = A + (size_t)(bm + ar) * DMODEL + k0 + akq * 8;
            f32x4 v0 = *(const f32x4*)src;
            f32x4 v1 = *(const f32x4*)(src + 4);
            short8 sv;
            for (int j = 0; j < 4; ++j) { sv[j] = f2bf(v0[j]); sv[4 + j] = f2bf(v1[j]); }
            *(short8*)&As[ar][akq * 8] = sv;
        }
        {
            const float* src = B + (size_t)(k0 + bkk) * DMODEL + bn + bng * 8;
            f32x4 v0 = *(const f32x4*)src;
            f32x4 v1 = *(const f32x4*)(src + 4);
            for (int j = 0; j < 4; ++j) {
                Bs[bng * 8 + j][bkk] = f2bf(v0[j]);
                Bs[bng * 8 + 4 + j][bkk] = f2bf(v1[j]);
            }
        }
        __syncthreads();
        int row = wid * 16 + (lane & 15);
        int koff = (lane >> 4) * 8;
        short8 a = *(const short8*)&As[row][koff];
        for (int nf = 0; nf < 4; ++nf) {
            int col = nf * 16 + (lane & 15);
            short8 b = *(const short8*)&Bs[col][koff];
            acc[nf] = __builtin_amdgcn_mfma_f32_16x16x32_bf16(a, b, acc[nf], 0, 0, 0);
        }
        __syncthreads();
    }
    for (int nf = 0; nf < 4; ++nf) {
        int col = bn + nf * 16 + (lane & 15);
        for (int j = 0; j < 4; ++j) {
            int row = bm + wid * 16 + (lane >> 4) * 4 + j;
            C[(size_t)row * DMODEL + col] =
                acc[nf][j] + bias[col] + residual[(size_t)row * DMODEL + col];
        }
    }
}

extern "C" void kernel_launch(void* const* d_in, const int* in_sizes, int n_in,
                              void* d_out, int out_size, void* d_ws, size_t ws_size,
                              hipStream_t stream) {
    const float* q = (const float*)d_in[0];
    const float* k = (const float*)d_in[1];
    const float* v = (const float*)d_in[2];
    const float* Wq = (const float*)d_in[3];
    const float* Wk = (const float*)d_in[4];
    const float* Wv = (const float*)d_in[5];
    const float* Wfc = (const float*)d_in[6];
    const float* bfc = (const float*)d_in[7];
    const float* gamma = (const float*)d_in[8];
    const float* beta = (const float*)d_in[9];
    const float* rf = (const float*)d_in[10];
    float* out = (float*)d_out;

    float* ws = (float*)d_ws;
    float* qn = ws;                                        // 2048*512 (reused as attn out)
    float* qh = qn + (size_t)NSEQ * DMODEL;                // 2048*512
    float* kh = qh + (size_t)NSEQ * DMODEL;                // 2048*512
    float* vhb = kh + (size_t)NSEQ * DMODEL;               // 2048*512
    short* qp = (short*)(vhb + (size_t)NSEQ * DMODEL);     // bf16 8*2048*288
    short* kp = qp + (size_t)NHEAD * NSEQ * MPAD;          // bf16 8*2048*288
    float* KVt = (float*)(kp + (size_t)NHEAD * NSEQ * MPAD);       // 8*32*64*288 fp32
    short* KVbT = (short*)(KVt + (size_t)NHEAD * NT * DV * MPAD);  // bf16 same extent
    float* Ks = (float*)(KVbT + (size_t)NHEAD * NT * DV * MPAD);   // 8*32*288
    float* Ktot = Ks + (size_t)NHEAD * NT * MPAD;          // 8*288
    float* hk = Ktot + (size_t)NHEAD * MPAD;               // 8*2048
    float* partial = hk + (size_t)NHEAD * NSEQ;            // 256
    float* kstab = partial + 256;                          // 4

    ln_kernel<<<NSEQ, 256, 0, stream>>>(q, gamma, beta, qn);
    dim3 gq(DMODEL / 64, NSEQ / 64, 3);
    qkv_kernel<<<gq, 256, 0, stream>>>(qn, k, v, Wq, Wk, Wv, qh, kh, vhb, hk, partial);
    maxreduce_kernel<<<1, 256, 0, stream>>>(partial, kstab);
    dim3 gf(5, NSEQ / 64, 16);
    feat_kernel<<<gf, 256, 0, stream>>>(qh, kh, rf, hk, kstab, qp, kp);
    dim3 ga(5, NT, NHEAD);
    chunksum_kernel<<<ga, 256, 0, stream>>>(kp, vhb, KVt, Ks);
    int scan_threads = NHEAD * DV * MPAD + NHEAD * MPAD;
    scan_kernel<<<(scan_threads + 255) / 256, 256, 0, stream>>>(KVt, KVbT, Ks, Ktot);
    dim3 gc(NT, NHEAD);
    phasec_kernel<<<gc, 256, 0, stream>>>(qp, kp, vhb, KVbT, Ks, Ktot, qn);
    dim3 g(DMODEL / 64, NSEQ / 64);
    fgemm_kernel<<<g, 256, 0, stream>>>(qn, Wfc, out, bfc, q);
}

// Round 7
// 110.948 us; speedup vs baseline: 16.3110x; 1.1658x over previous
//
#include <hip/hip_runtime.h>
#include <math.h>

#define DMODEL 512
#define NSEQ 2048
#define NHEAD 8
#define DK 64
#define DV 64
#define MFEAT 266
#define MPAD 288        // padded feature dim for bf16 MFMA (zero tail), mult of 32
#define NT 32           // number of chunks (chunk = 64)
#define LN_EPS 1e-6f
#define KERNEL_EPS 1e-4f
#define NORM_STAB 1e-6f
#define SCALE 0.21022410381342863f  // 512^-0.25

typedef __attribute__((ext_vector_type(8))) short short8;
typedef __attribute__((ext_vector_type(4))) short sv4;
typedef __attribute__((ext_vector_type(4))) float f32x4;

__device__ inline short f2bf(float f) {
    unsigned u = __builtin_bit_cast(unsigned, f);
    unsigned r = (u + 0x7fff + ((u >> 16) & 1)) >> 16;
    return (short)r;
}
__device__ inline float bf2f(short s) {
    unsigned u = ((unsigned)(unsigned short)s) << 16;
    return __builtin_bit_cast(float, u);
}

// ---------------- LN stats: per-row mu, rstd (one wave per row) ----------------
__global__ __launch_bounds__(256) void ln_stats_kernel(const float* __restrict__ q,
                                                       float* __restrict__ mu,
                                                       float* __restrict__ rstd) {
    int row = blockIdx.x * 4 + (threadIdx.x >> 6);
    int lane = threadIdx.x & 63;
    const float* x = q + (size_t)row * DMODEL + lane * 8;
    f32x4 a = *(const f32x4*)x;
    f32x4 b = *(const f32x4*)(x + 4);
    float s = a[0] + a[1] + a[2] + a[3] + b[0] + b[1] + b[2] + b[3];
    float ss = a[0]*a[0] + a[1]*a[1] + a[2]*a[2] + a[3]*a[3]
             + b[0]*b[0] + b[1]*b[1] + b[2]*b[2] + b[3]*b[3];
    for (int o = 32; o > 0; o >>= 1) {
        s += __shfl_down(s, o);
        ss += __shfl_down(ss, o);
    }
    if (lane == 0) {
        float m = s / (float)DMODEL;
        float var = ss / (float)DMODEL - m * m;
        mu[row] = m;
        rstd[row] = rsqrtf(var + LN_EPS);
    }
}

// ---------------- fused QKV bf16 MFMA GEMM; z=0 applies LN during A staging; z=1 emits h_k ----------------
__global__ __launch_bounds__(256) void qkv_kernel(const float* __restrict__ qx,
                                                  const float* __restrict__ kx,
                                                  const float* __restrict__ vx,
                                                  const float* __restrict__ Wq,
                                                  const float* __restrict__ Wk,
                                                  const float* __restrict__ Wv,
                                                  const float* __restrict__ mu,
                                                  const float* __restrict__ rstd,
                                                  const float* __restrict__ gamma,
                                                  const float* __restrict__ beta,
                                                  float* __restrict__ qh,
                                                  float* __restrict__ kh,
                                                  float* __restrict__ vh,
                                                  float* __restrict__ hk,
                                                  float* __restrict__ partial) {
    int z = blockIdx.z;
    const float* A = (z == 0) ? qx : (z == 1) ? kx : vx;
    const float* B = (z == 0) ? Wq : (z == 1) ? Wk : Wv;
    float* C = (z == 0) ? qh : (z == 1) ? kh : vh;
    float scale = (z == 2) ? 1.f : SCALE;

    __shared__ short As[64][40];
    __shared__ short Bs[64][40];
    int bm = blockIdx.y * 64, bn = blockIdx.x * 64;
    int tid = threadIdx.x;
    int wid = tid >> 6, lane = tid & 63;
    f32x4 acc[4] = {f32x4{0,0,0,0}, f32x4{0,0,0,0}, f32x4{0,0,0,0}, f32x4{0,0,0,0}};
    int ar = tid >> 2, akq = tid & 3;
    int bkk = tid >> 3, bng = tid & 7;
    float lnm = 0.f, lnr = 0.f;
    if (z == 0) { lnm = mu[bm + ar]; lnr = rstd[bm + ar]; }
    for (int k0 = 0; k0 < DMODEL; k0 += 32) {
        {
            const float* src = A + (size_t)(bm + ar) * DMODEL + k0 + akq * 8;
            f32x4 v0 = *(const f32x4*)src;
            f32x4 v1 = *(const f32x4*)(src + 4);
            short8 sv;
            if (z == 0) {
                f32x4 g0 = *(const f32x4*)&gamma[k0 + akq * 8];
                f32x4 g1 = *(const f32x4*)&gamma[k0 + akq * 8 + 4];
                f32x4 bb0 = *(const f32x4*)&beta[k0 + akq * 8];
                f32x4 bb1 = *(const f32x4*)&beta[k0 + akq * 8 + 4];
                for (int j = 0; j < 4; ++j) {
                    sv[j] = f2bf((v0[j] - lnm) * lnr * g0[j] + bb0[j]);
                    sv[4 + j] = f2bf((v1[j] - lnm) * lnr * g1[j] + bb1[j]);
                }
            } else {
                for (int j = 0; j < 4; ++j) { sv[j] = f2bf(v0[j]); sv[4 + j] = f2bf(v1[j]); }
            }
            *(short8*)&As[ar][akq * 8] = sv;
        }
        {
            const float* src = B + (size_t)(k0 + bkk) * DMODEL + bn + bng * 8;
            f32x4 v0 = *(const f32x4*)src;
            f32x4 v1 = *(const f32x4*)(src + 4);
            for (int j = 0; j < 4; ++j) {
                Bs[bng * 8 + j][bkk] = f2bf(v0[j] * scale);
                Bs[bng * 8 + 4 + j][bkk] = f2bf(v1[j] * scale);
            }
        }
        __syncthreads();
        int row = wid * 16 + (lane & 15);
        int koff = (lane >> 4) * 8;
        short8 a = *(const short8*)&As[row][koff];
        for (int nf = 0; nf < 4; ++nf) {
            int col = nf * 16 + (lane & 15);
            short8 b = *(const short8*)&Bs[col][koff];
            acc[nf] = __builtin_amdgcn_mfma_f32_16x16x32_bf16(a, b, acc[nf], 0, 0, 0);
        }
        __syncthreads();
    }
    for (int nf = 0; nf < 4; ++nf) {
        int col = bn + nf * 16 + (lane & 15);
        for (int j = 0; j < 4; ++j) {
            int row = bm + wid * 16 + (lane >> 4) * 4 + j;
            C[(size_t)row * DMODEL + col] = acc[nf][j];
        }
    }
    if (z == 1) {
        __shared__ float bmax[4];
        float hvmax = -1e30f;
        for (int j = 0; j < 4; ++j) {
            float ss = 0.f;
            for (int nf = 0; nf < 4; ++nf) ss += acc[nf][j] * acc[nf][j];
            for (int o = 1; o < 16; o <<= 1) ss += __shfl_xor(ss, o);
            float hv = -0.5f * ss;
            int row = bm + wid * 16 + (lane >> 4) * 4 + j;
            if ((lane & 15) == 0) hk[(size_t)blockIdx.x * NSEQ + row] = hv;
            hvmax = fmaxf(hvmax, hv);
        }
        for (int o = 32; o > 0; o >>= 1) hvmax = fmaxf(hvmax, __shfl_down(hvmax, o));
        if (lane == 0) bmax[wid] = hvmax;
        __syncthreads();
        if (tid == 0)
            partial[blockIdx.y * 8 + blockIdx.x] =
                fmaxf(fmaxf(bmax[0], bmax[1]), fmaxf(bmax[2], bmax[3]));
    }
}

// ---------------- MFMA random feature maps -> bf16 [h][n][MPAD]; grid (nt, h, isQ) ----------------
__global__ __launch_bounds__(256) void feat_kernel(const float* __restrict__ qh,
                                                   const float* __restrict__ kh,
                                                   const float* __restrict__ rf,
                                                   const float* __restrict__ hkv,
                                                   const float* __restrict__ partial,
                                                   short* __restrict__ qp,
                                                   short* __restrict__ kp) {
    int nt = blockIdx.x, h = blockIdx.y, isQ = blockIdx.z;
    int n0 = nt * 64;
    int tid = threadIdx.x, w = tid >> 6, l = tid & 63;
    __shared__ short U[288 * 72];   // union: rfb[288][72] then kp_lds[64][296]
    __shared__ short Xs[64][72];
    __shared__ float red[4];

    // inline kstab reduce (partial[256] written by qkv z=1)
    float pm = partial[tid];
    for (int o = 32; o > 0; o >>= 1) pm = fmaxf(pm, __shfl_down(pm, o));
    if (l == 0) red[w] = pm;

    // stage rf -> bf16 rfb[m][d] (zero for m>=MFEAT)
    short (*rfb)[72] = (short(*)[72])U;
    for (int lp = 0; lp < 5; ++lp) {
        int c = tid + lp * 256;
        if (c < 288 * 4) {
            int m = c >> 2, dq = (c & 3) * 16;
            short8 s0, s1;
            if (m < MFEAT) {
                f32x4 v0 = *(const f32x4*)&rf[(size_t)m * DK + dq];
                f32x4 v1 = *(const f32x4*)&rf[(size_t)m * DK + dq + 4];
                f32x4 v2 = *(const f32x4*)&rf[(size_t)m * DK + dq + 8];
                f32x4 v3 = *(const f32x4*)&rf[(size_t)m * DK + dq + 12];
                for (int j = 0; j < 4; ++j) {
                    s0[j] = f2bf(v0[j]); s0[4 + j] = f2bf(v1[j]);
                    s1[j] = f2bf(v2[j]); s1[4 + j] = f2bf(v3[j]);
                }
            } else {
                for (int j = 0; j < 8; ++j) { s0[j] = 0; s1[j] = 0; }
            }
            *(short8*)&rfb[m][dq] = s0;
            *(short8*)&rfb[m][dq + 8] = s1;
        }
    }
    // stage X chunk -> bf16 Xs[n][d]
    const float* xh = isQ ? qh : kh;
    {
        int n = tid >> 2, dq = (tid & 3) * 16;
        const float* src = xh + (size_t)(n0 + n) * DMODEL + h * DK + dq;
        f32x4 v0 = *(const f32x4*)src;
        f32x4 v1 = *(const f32x4*)(src + 4);
        f32x4 v2 = *(const f32x4*)(src + 8);
        f32x4 v3 = *(const f32x4*)(src + 12);
        short8 s0, s1;
        for (int j = 0; j < 4; ++j) {
            s0[j] = f2bf(v0[j]); s0[4 + j] = f2bf(v1[j]);
            s1[j] = f2bf(v2[j]); s1[4 + j] = f2bf(v3[j]);
        }
        *(short8*)&Xs[n][dq] = s0;
        *(short8*)&Xs[n][dq + 8] = s1;
    }
    __syncthreads();
    float ks = fmaxf(fmaxf(red[0], red[1]), fmaxf(red[2], red[3]));

    // proj MFMA: C[m][n] = sum_d rfb[m][d] * Xs[n][d]; wave w owns n-tile w
    int fr = l & 15, fq = (l >> 4) * 8;
    short8 xb0 = *(const short8*)&Xs[w * 16 + fr][fq];
    short8 xb1 = *(const short8*)&Xs[w * 16 + fr][32 + fq];
    f32x4 acc[18];
#pragma unroll
    for (int tr = 0; tr < 18; ++tr) acc[tr] = f32x4{0, 0, 0, 0};
#pragma unroll
    for (int tr = 0; tr < 18; ++tr) {
        short8 a0 = *(const short8*)&rfb[tr * 16 + fr][fq];
        short8 a1 = *(const short8*)&rfb[tr * 16 + fr][32 + fq];
        acc[tr] = __builtin_amdgcn_mfma_f32_16x16x32_bf16(a0, xb0, acc[tr], 0, 0, 0);
        acc[tr] = __builtin_amdgcn_mfma_f32_16x16x32_bf16(a1, xb1, acc[tr], 0, 0, 0);
    }
    __syncthreads();  // all waves done reading rfb; U becomes kp_lds

    short (*kpl)[296] = (short(*)[296])U;
    int n_loc = w * 16 + fr;
    int n = n0 + n_loc;
    const float cnorm = 0.06131393394849658f;  // 266^-0.5
    float hval = isQ ? 0.f : (hkv[(size_t)h * NSEQ + n] - ks);
#pragma unroll
    for (int tr = 0; tr < 18; ++tr) {
        sv4 o;
        for (int j = 0; j < 4; ++j) {
            int m = tr * 16 + (l >> 4) * 4 + j;
            float val = (m < MFEAT) ? cnorm * (expf(acc[tr][j] + hval) + KERNEL_EPS) : 0.f;
            o[j] = f2bf(val);
        }
        *(sv4*)&kpl[n_loc][tr * 16 + (l >> 4) * 4] = o;
    }
    __syncthreads();
    // coalesced copy kp_lds rows -> HBM
    short* outp = isQ ? qp : kp;
    for (int lp = 0; lp < 9; ++lp) {
        int c = tid + lp * 256;      // 64 rows * 36 chunks
        int nn = c / 36, c8 = c % 36;
        short8 v = *(const short8*)&kpl[nn][c8 * 8];
        *(short8*)&outp[((size_t)h * NSEQ + n0 + nn) * MPAD + c8 * 8] = v;
    }
}

// ---------------- phase A: per-chunk sums, transposed KVt[(h,t,dv)][m], Ks[(h,t)][m] ----------------
__global__ __launch_bounds__(256) void chunksum_kernel(const short* __restrict__ kp,
                                                       const float* __restrict__ vh,
                                                       float* __restrict__ KVt,
                                                       float* __restrict__ Ks) {
    int mt = blockIdx.x, t = blockIdx.y, h = blockIdx.z;
    int m0 = mt * 64;
    int tid = threadIdx.x;
    int tx = tid & 15, ty = tid >> 4;
    __shared__ float Kl[64][68];  // [i][mloc]
    __shared__ float Vl[64][68];  // [i][dv]
    for (int l = 0; l < 2; ++l) {
        int idx = tid + l * 256;
        int i = idx >> 3, c8 = idx & 7;
        int m = m0 + c8 * 8;
        float vals[8] = {0.f, 0.f, 0.f, 0.f, 0.f, 0.f, 0.f, 0.f};
        if (m + 7 < MPAD) {
            short8 sv = *(const short8*)&kp[((size_t)h * NSEQ + t * 64 + i) * MPAD + m];
            for (int j = 0; j < 8; ++j) vals[j] = bf2f(sv[j]);
        }
        for (int j = 0; j < 8; ++j) Kl[i][c8 * 8 + j] = vals[j];
    }
    for (int l = 0; l < 4; ++l) {
        int idx = tid + l * 256;
        int i = idx >> 4, q4 = idx & 15;
        f32x4 vv = *(const f32x4*)&vh[(size_t)(t * 64 + i) * DMODEL + h * DV + q4 * 4];
        *(f32x4*)&Vl[i][q4 * 4] = vv;
    }
    __syncthreads();
    float acc[4][4] = {};
#pragma unroll 4
    for (int i = 0; i < 64; ++i) {
        f32x4 a = *(const f32x4*)&Kl[i][ty * 4];
        f32x4 b = *(const f32x4*)&Vl[i][tx * 4];
        for (int r = 0; r < 4; ++r)
            for (int c = 0; c < 4; ++c) acc[r][c] += a[r] * b[c];
    }
    int m = m0 + ty * 4;
    if (m < MPAD) {
        for (int c = 0; c < 4; ++c) {
            int dv = tx * 4 + c;
            f32x4 o = {acc[0][c], acc[1][c], acc[2][c], acc[3][c]};
            *(f32x4*)&KVt[(((size_t)h * NT + t) * DV + dv) * MPAD + m] = o;
        }
    }
    if (tid < 64) {
        int ms = m0 + tid;
        if (ms < MPAD) {
            float s = 0.f;
#pragma unroll 8
            for (int i = 0; i < 64; ++i) s += Kl[i][tid];
            Ks[((size_t)h * NT + t) * MPAD + ms] = s;
        }
    }
}

// ---------------- fused exclusive chunk-scans (KV -> bf16 S^T, Ks -> prefix + Ktot) ----------------
__global__ void scan_kernel(const float* __restrict__ KVt, short* __restrict__ KVbT,
                            float* __restrict__ Ks, float* __restrict__ Ktot) {
    int idx = blockIdx.x * 256 + threadIdx.x;
    const int NKV = NHEAD * DV * MPAD;       // 147456
    if (idx < NKV) {
        int h = idx / (DV * MPAD);
        int rem = idx % (DV * MPAD);
        size_t base = (size_t)h * NT * DV * MPAD + rem;
        float run = 0.f;
        for (int t = 0; t < NT; ++t) {
            size_t o = base + (size_t)t * DV * MPAD;
            KVbT[o] = f2bf(run);
            run += KVt[o];
        }
    } else {
        int j = idx - NKV;
        if (j < NHEAD * MPAD) {
            int h = j / MPAD, m = j % MPAD;
            size_t base = (size_t)h * NT * MPAD + m;
            float run = 0.f;
            for (int t = 0; t < NT; ++t) {
                size_t o = base + (size_t)t * MPAD;
                float v = Ks[o];
                Ks[o] = run;
                run += v;
            }
            Ktot[(size_t)h * MPAD + m] = run;
        }
    }
}

// ---------------- phase C: MFMA intra+inter+denominators ----------------
__global__ __launch_bounds__(256) void phasec_kernel(const short* __restrict__ qp,
                                                     const short* __restrict__ kp,
                                                     const float* __restrict__ vh,
                                                     const short* __restrict__ KVbT,
                                                     const float* __restrict__ Ks,
                                                     const float* __restrict__ Ktot,
                                                     float* __restrict__ attn) {
    int t = blockIdx.x, h = blockIdx.y;
    __shared__ short Buf[64][296];   // Kp (QK^T phase) then St (inter phase)
    __shared__ short Vt[64][72];     // [dv][i]
    __shared__ short Am[64][72];     // masked A, bf16
    __shared__ float Ksp[MPAD], Ktp[MPAD];
    __shared__ float fscale_s[64];
    int tid = threadIdx.x;
    int w = tid >> 6, l = tid & 63;
    int fr = l & 15, fq = (l >> 4) * 8;
    const short* qpb = qp + ((size_t)h * NSEQ + (size_t)t * 64) * MPAD;
    const short* kpb = kp + ((size_t)h * NSEQ + (size_t)t * 64) * MPAD;
    const short* stb = KVbT + ((size_t)h * NT + t) * DV * MPAD;

    short8 qf[9];
#pragma unroll
    for (int ks = 0; ks < 9; ++ks)
        qf[ks] = *(const short8*)&qpb[(size_t)(w * 16 + fr) * MPAD + ks * 32 + fq];

    int srow = tid >> 2, sc4 = tid & 3;
#pragma unroll
    for (int lp = 0; lp < 9; ++lp) {
        int c = sc4 + lp * 4;
        *(short8*)&Buf[srow][c * 8] = *(const short8*)&kpb[(size_t)srow * MPAD + c * 8];
    }
    {
        int dv = tid >> 2, iq = (tid & 3) * 16;
        short8 v0, v1;
        for (int it = 0; it < 8; ++it)
            v0[it] = f2bf(vh[(size_t)(t * 64 + iq + it) * DMODEL + h * DV + dv]);
        for (int it = 0; it < 8; ++it)
            v1[it] = f2bf(vh[(size_t)(t * 64 + iq + 8 + it) * DMODEL + h * DV + dv]);
        *(short8*)&Vt[dv][iq] = v0;
        *(short8*)&Vt[dv][iq + 8] = v1;
    }
    for (int idx = tid; idx < MPAD; idx += 256) {
        Ksp[idx] = Ks[((size_t)h * NT + t) * MPAD + idx];
        Ktp[idx] = Ktot[(size_t)h * MPAD + idx];
    }
    __syncthreads();

    f32x4 accA[4] = {f32x4{0,0,0,0}, f32x4{0,0,0,0}, f32x4{0,0,0,0}, f32x4{0,0,0,0}};
    f32x4 accO[4] = {f32x4{0,0,0,0}, f32x4{0,0,0,0}, f32x4{0,0,0,0}, f32x4{0,0,0,0}};
#pragma unroll 3
    for (int ks = 0; ks < 9; ++ks) {
        int ko = ks * 32 + fq;
        for (int nf = 0; nf < 4; ++nf) {
            short8 bk = *(const short8*)&Buf[nf * 16 + fr][ko];
            accA[nf] = __builtin_amdgcn_mfma_f32_16x16x32_bf16(qf[ks], bk, accA[nf], 0, 0, 0);
        }
    }
    __syncthreads();
#pragma unroll
    for (int lp = 0; lp < 9; ++lp) {
        int c = sc4 + lp * 4;
        *(short8*)&Buf[srow][c * 8] = *(const short8*)&stb[(size_t)srow * MPAD + c * 8];
    }
    for (int nf = 0; nf < 4; ++nf) {
        int col = nf * 16 + fr;
        for (int j = 0; j < 4; ++j) {
            int row = w * 16 + (l >> 4) * 4 + j;
            Am[row][col] = (col <= row) ? f2bf(accA[nf][j]) : (short)0;
        }
    }
    __syncthreads();
#pragma unroll 3
    for (int ks = 0; ks < 9; ++ks) {
        int ko = ks * 32 + fq;
        for (int nf = 0; nf < 4; ++nf) {
            short8 bs = *(const short8*)&Buf[nf * 16 + fr][ko];
            accO[nf] = __builtin_amdgcn_mfma_f32_16x16x32_bf16(qf[ks], bs, accO[nf], 0, 0, 0);
        }
    }
#pragma unroll
    for (int ks = 0; ks < 2; ++ks) {
        int ko = ks * 32 + fq;
        short8 a = *(const short8*)&Am[w * 16 + fr][ko];
        for (int nf = 0; nf < 4; ++nf) {
            short8 b = *(const short8*)&Vt[nf * 16 + fr][ko];
            accO[nf] = __builtin_amdgcn_mfma_f32_16x16x32_bf16(a, b, accO[nf], 0, 0, 0);
        }
    }
    int di = tid >> 2, dp = tid & 3;
    float dc = 0.f, df = 0.f;
    {
        const short* amrow = &Am[di][dp * 16];
        short8 s0 = *(const short8*)amrow;
        short8 s1 = *(const short8*)(amrow + 8);
        for (int j2 = 0; j2 < 8; ++j2) dc += bf2f(s0[j2]) + bf2f(s1[j2]);
    }
#pragma unroll
    for (int c8 = 0; c8 < 9; ++c8) {
        int m = dp * 72 + c8 * 8;
        short8 qv = *(const short8*)&qpb[(size_t)di * MPAD + m];
        for (int j2 = 0; j2 < 8; ++j2) {
            float qq = bf2f(qv[j2]);
            dc += qq * Ksp[m + j2];
            df += qq * Ktp[m + j2];
        }
    }
    dc += __shfl_xor(dc, 1); dc += __shfl_xor(dc, 2);
    df += __shfl_xor(df, 1); df += __shfl_xor(df, 2);
    if (dp == 0) {
        float dst = df;
        if (fabsf(dst) <= NORM_STAB) dst += 2.f * NORM_STAB;
        fscale_s[di] = (1.f / dc) / dst;
    }
    __syncthreads();
    for (int nf = 0; nf < 4; ++nf) {
        int col = nf * 16 + fr;
        for (int j = 0; j < 4; ++j) {
            int row = w * 16 + (l >> 4) * 4 + j;
            attn[((size_t)t * 64 + row) * DMODEL + h * DV + col] = accO[nf][j] * fscale_s[row];
        }
    }
}

// ---------------- final GEMM with bias + residual ----------------
__global__ __launch_bounds__(256) void fgemm_kernel(const float* __restrict__ A,
                                                    const float* __restrict__ B,
                                                    float* __restrict__ C,
                                                    const float* __restrict__ bias,
                                                    const float* __restrict__ residual) {
    __shared__ short As[64][40];
    __shared__ short Bs[64][40];
    int bm = blockIdx.y * 64, bn = blockIdx.x * 64;
    int tid = threadIdx.x;
    int wid = tid >> 6, lane = tid & 63;
    f32x4 acc[4] = {f32x4{0,0,0,0}, f32x4{0,0,0,0}, f32x4{0,0,0,0}, f32x4{0,0,0,0}};
    int ar = tid >> 2, akq = tid & 3;
    int bkk = tid >> 3, bng = tid & 7;
    for (int k0 = 0; k0 < DMODEL; k0 += 32) {
        {
            const float* src = A + (size_t)(bm + ar) * DMODEL + k0 + akq * 8;
            f32x4 v0 = *(const f32x4*)src;
            f32x4 v1 = *(const f32x4*)(src + 4);
            short8 sv;
            for (int j = 0; j < 4; ++j) { sv[j] = f2bf(v0[j]); sv[4 + j] = f2bf(v1[j]); }
            *(short8*)&As[ar][akq * 8] = sv;
        }
        {
            const float* src = B + (size_t)(k0 + bkk) * DMODEL + bn + bng * 8;
            f32x4 v0 = *(const f32x4*)src;
            f32x4 v1 = *(const f32x4*)(src + 4);
            for (int j = 0; j < 4; ++j) {
                Bs[bng * 8 + j][bkk] = f2bf(v0[j]);
                Bs[bng * 8 + 4 + j][bkk] = f2bf(v1[j]);
            }
        }
        __syncthreads();
        int row = wid * 16 + (lane & 15);
        int koff = (lane >> 4) * 8;
        short8 a = *(const short8*)&As[row][koff];
        for (int nf = 0; nf < 4; ++nf) {
            int col = nf * 16 + (lane & 15);
            short8 b = *(const short8*)&Bs[col][koff];
            acc[nf] = __builtin_amdgcn_mfma_f32_16x16x32_bf16(a, b, acc[nf], 0, 0, 0);
        }
        __syncthreads();
    }
    for (int nf = 0; nf < 4; ++nf) {
        int col = bn + nf * 16 + (lane & 15);
        for (int j = 0; j < 4; ++j) {
            int row = bm + wid * 16 + (lane >> 4) * 4 + j;
            C[(size_t)row * DMODEL + col] =
                acc[nf][j] + bias[col] + residual[(size_t)row * DMODEL + col];
        }
    }
}

extern "C" void kernel_launch(void* const* d_in, const int* in_sizes, int n_in,
                              void* d_out, int out_size, void* d_ws, size_t ws_size,
                              hipStream_t stream) {
    const float* q = (const float*)d_in[0];
    const float* k = (const float*)d_in[1];
    const float* v = (const float*)d_in[2];
    const float* Wq = (const float*)d_in[3];
    const float* Wk = (const float*)d_in[4];
    const float* Wv = (const float*)d_in[5];
    const float* Wfc = (const float*)d_in[6];
    const float* bfc = (const float*)d_in[7];
    const float* gamma = (const float*)d_in[8];
    const float* beta = (const float*)d_in[9];
    const float* rf = (const float*)d_in[10];
    float* out = (float*)d_out;

    float* ws = (float*)d_ws;
    float* attn = ws;                                      // 2048*512
    float* qh = attn + (size_t)NSEQ * DMODEL;              // 2048*512
    float* kh = qh + (size_t)NSEQ * DMODEL;                // 2048*512
    float* vhb = kh + (size_t)NSEQ * DMODEL;               // 2048*512
    short* qp = (short*)(vhb + (size_t)NSEQ * DMODEL);     // bf16 8*2048*288
    short* kp = qp + (size_t)NHEAD * NSEQ * MPAD;          // bf16 8*2048*288
    float* KVt = (float*)(kp + (size_t)NHEAD * NSEQ * MPAD);       // 8*32*64*288 fp32
    short* KVbT = (short*)(KVt + (size_t)NHEAD * NT * DV * MPAD);  // bf16 same extent
    float* Ks = (float*)(KVbT + (size_t)NHEAD * NT * DV * MPAD);   // 8*32*288
    float* Ktot = Ks + (size_t)NHEAD * NT * MPAD;          // 8*288
    float* hk = Ktot + (size_t)NHEAD * MPAD;               // 8*2048
    float* partial = hk + (size_t)NHEAD * NSEQ;            // 256
    float* mu = partial + 256;                             // 2048
    float* rstd = mu + NSEQ;                               // 2048

    ln_stats_kernel<<<NSEQ / 4, 256, 0, stream>>>(q, mu, rstd);
    dim3 gq(DMODEL / 64, NSEQ / 64, 3);
    qkv_kernel<<<gq, 256, 0, stream>>>(q, k, v, Wq, Wk, Wv, mu, rstd, gamma, beta,
                                       qh, kh, vhb, hk, partial);
    dim3 gf(NT, NHEAD, 2);
    feat_kernel<<<gf, 256, 0, stream>>>(qh, kh, rf, hk, partial, qp, kp);
    dim3 ga(5, NT, NHEAD);
    chunksum_kernel<<<ga, 256, 0, stream>>>(kp, vhb, KVt, Ks);
    int scan_threads = NHEAD * DV * MPAD + NHEAD * MPAD;
    scan_kernel<<<(scan_threads + 255) / 256, 256, 0, stream>>>(KVt, KVbT, Ks, Ktot);
    dim3 gc(NT, NHEAD);
    phasec_kernel<<<gc, 256, 0, stream>>>(qp, kp, vhb, KVbT, Ks, Ktot, attn);
    dim3 g(DMODEL / 64, NSEQ / 64);
    fgemm_kernel<<<g, 256, 0, stream>>>(attn, Wfc, out, bfc, q);
}